// Round 10
// baseline (342.793 us; speedup 1.0000x reference)
//
#include <hip/hip_runtime.h>
#include <hip/hip_bf16.h>

// ---------------------------------------------------------------------------
// AttentionBlock: qkv-proj (+LN on q,k) -> masked flash attention -> out-proj
// B=2, S=2048, E=2048, H=16, D=128. GEMMs: bf16 MFMA 16x16x32 (m97 structure).
// Attention: bf16 MFMA 32x32x16, swapped QK^T, exp2-domain softmax, dbuf LDS
// with COUNTED vmcnt (T4): stage loads stay in flight across barriers.
// V^T is produced directly by a swapped-operand GEMM (MODE 4) with the
// key-position permutation baked into the store.
// ---------------------------------------------------------------------------

typedef __attribute__((ext_vector_type(8))) __bf16 bf16x8;
typedef __attribute__((ext_vector_type(4))) float f32x4;
typedef __attribute__((ext_vector_type(16))) float f32x16;
typedef __attribute__((ext_vector_type(8))) unsigned short ushort8;
typedef __attribute__((ext_vector_type(4))) unsigned short ushort4v;
typedef __attribute__((ext_vector_type(4))) unsigned uint4v;
typedef __attribute__((ext_vector_type(4))) float float4v;

#define MFMA16(a, b, c) __builtin_amdgcn_mfma_f32_16x16x32_bf16((a), (b), (c), 0, 0, 0)
#define MFMA32(a, b, c) __builtin_amdgcn_mfma_f32_32x32x16_bf16((a), (b), (c), 0, 0, 0)

__device__ __forceinline__ unsigned short f2bf(float f) {
  unsigned u = __builtin_bit_cast(unsigned, f);
  u += 0x7fffu + ((u >> 16) & 1u);           // RNE
  return (unsigned short)(u >> 16);
}

__device__ __forceinline__ unsigned pkbf(float lo, float hi) {  // bf16(lo)|bf16(hi)<<16
  unsigned d;
  asm("v_cvt_pk_bf16_f32 %0, %1, %2" : "=v"(d) : "v"(lo), "v"(hi));
  return d;
}

__device__ __forceinline__ float max3f(float a, float b, float c) {
  float d;
  asm("v_max3_f32 %0, %1, %2, %3" : "=v"(d) : "v"(a), "v"(b), "v"(c));
  return d;
}

__device__ __forceinline__ float exp2a(float x) {  // 2^x
  float d;
  asm("v_exp_f32 %0, %1" : "=v"(d) : "v"(x));
  return d;
}

__device__ __forceinline__ void gload_lds16(const void* g, void* l) {
  __builtin_amdgcn_global_load_lds(
      (const __attribute__((address_space(1))) void*)g,
      (__attribute__((address_space(3))) void*)l, 16, 0, 0);
}

// ---------------- prep: elementwise add + fp32->bf16 -----------------------
__global__ __launch_bounds__(256) void k_cvt(const float4v* __restrict__ x,
                                             const float4v* __restrict__ y,
                                             ushort4v* __restrict__ o, int n4) {
  int i = blockIdx.x * 256 + threadIdx.x;
  if (i >= n4) return;
  float4v a = x[i];
  if (y) { float4v b = y[i]; a = a + b; }
  ushort4v r;
  r[0] = f2bf(a[0]); r[1] = f2bf(a[1]); r[2] = f2bf(a[2]); r[3] = f2bf(a[3]);
  o[i] = r;
}

// ---------------- prep: kv -> a_k (kv+kv_pos) and a_v (kv) in one pass -----
__global__ __launch_bounds__(256) void k_cvt2(const float4v* __restrict__ x,
                                              const float4v* __restrict__ y,
                                              ushort4v* __restrict__ oa,
                                              ushort4v* __restrict__ ob, int n4) {
  int i = blockIdx.x * 256 + threadIdx.x;
  if (i >= n4) return;
  float4v a = x[i];
  float4v s = a + y[i];
  ushort4v ra, rb;
  ra[0] = f2bf(s[0]); ra[1] = f2bf(s[1]); ra[2] = f2bf(s[2]); ra[3] = f2bf(s[3]);
  rb[0] = f2bf(a[0]); rb[1] = f2bf(a[1]); rb[2] = f2bf(a[2]); rb[3] = f2bf(a[3]);
  oa[i] = ra; ob[i] = rb;
}

// ---------------- prep: weight transpose fp32[K][N] -> bf16[N][K] ----------
__global__ __launch_bounds__(256) void k_tr(const float* __restrict__ s0, const float* __restrict__ s1,
                                            const float* __restrict__ s2, const float* __restrict__ s3,
                                            unsigned short* __restrict__ d0, unsigned short* __restrict__ d1,
                                            unsigned short* __restrict__ d2, unsigned short* __restrict__ d3) {
  __shared__ float t[32][33];
  const float* S; unsigned short* D;
  switch (blockIdx.z) {
    case 0: S = s0; D = d0; break;
    case 1: S = s1; D = d1; break;
    case 2: S = s2; D = d2; break;
    default: S = s3; D = d3; break;
  }
  int x = threadIdx.x & 31, y = threadIdx.x >> 5;
  int r0 = blockIdx.y * 32, c0 = blockIdx.x * 32;
#pragma unroll
  for (int i = 0; i < 4; ++i) t[y + 8 * i][x] = S[(size_t)(r0 + y + 8 * i) * 2048 + c0 + x];
  __syncthreads();
#pragma unroll
  for (int i = 0; i < 4; ++i)
    D[(size_t)(c0 + y + 8 * i) * 2048 + r0 + x] = f2bf(t[x][y + 8 * i]);
}

// ---------------- prep: mask int32 -> bitmask (1 bit/key) ------------------
__global__ __launch_bounds__(256) void k_mask(const int* __restrict__ m,
                                              unsigned long long* __restrict__ out) {
  int i = blockIdx.x * 256 + threadIdx.x;
  unsigned long long b = __ballot(m[i] != 0);
  if ((threadIdx.x & 63) == 0) out[i >> 6] = b;
}

// ---------------- GEMM 128x128 tile, BK=64, 4 waves (m97 structure) --------
// MODE 1: LN*scale*rsqrt(D)*log2e (Q) -> [B,H,S,D] bf16
// MODE 2: LN*scale (K)               -> [B,H,S,D] bf16
// MODE 3: fp32 direct to [4096][2048] (final out-proj)
// MODE 4: V^T direct: A=wvt (M=2048=(h,d)), Bt=a_v (N=4096=(b,s));
//         store at Vtp[bh][d][(s&~15)|swap23(s&15)] bf16.
template <int MODE>
__global__ __launch_bounds__(256) void k_gemm(const unsigned short* __restrict__ A,
                                              const unsigned short* __restrict__ Bt,
                                              void* __restrict__ Cv,
                                              const float* __restrict__ lnsc) {
  constexpr int K = 2048;
  __shared__ __attribute__((aligned(16))) unsigned short sA[128 * 64];
  __shared__ __attribute__((aligned(16))) unsigned short sB[128 * 64];
  __shared__ float sSum[2][128];
  __shared__ float sSq[2][128];
  int tid = threadIdx.x;
  int lane = tid & 63, w = tid >> 6;
  int wr = w >> 1, wc = w & 1;
  int r15 = lane & 15, blk = lane >> 4;
  int n0 = blockIdx.x * 128, m0 = blockIdx.y * 128;
  const unsigned short* Abase = A + (size_t)m0 * K;
  const unsigned short* Bbase = Bt + (size_t)n0 * K;
  f32x4 acc[4][4] = {};

  for (int kt = 0; kt < K; kt += 64) {
#pragma unroll
    for (int i = 0; i < 4; ++i) {   // stage A tile: 1024 16B chunks, XOR-swizzled source
      int c = i * 256 + tid;
      int row = c >> 3, cc = c & 7;
      gload_lds16(Abase + (size_t)row * K + kt + ((cc ^ (row & 7)) * 8), &sA[c * 8]);
    }
#pragma unroll
    for (int i = 0; i < 4; ++i) {   // stage B tile
      int c = i * 256 + tid;
      int row = c >> 3, cc = c & 7;
      gload_lds16(Bbase + (size_t)row * K + kt + ((cc ^ (row & 7)) * 8), &sB[c * 8]);
    }
    __syncthreads();
#pragma unroll
    for (int kk = 0; kk < 2; ++kk) {
      bf16x8 av[4], bv[4];
#pragma unroll
      for (int i = 0; i < 4; ++i) {
        int row = wr * 64 + i * 16 + r15;
        av[i] = *(const bf16x8*)&sA[row * 64 + (((kk * 4 + blk) ^ (row & 7)) * 8)];
      }
#pragma unroll
      for (int j = 0; j < 4; ++j) {
        int row = wc * 64 + j * 16 + r15;
        bv[j] = *(const bf16x8*)&sB[row * 64 + (((kk * 4 + blk) ^ (row & 7)) * 8)];
      }
#pragma unroll
      for (int i = 0; i < 4; ++i)
#pragma unroll
        for (int j = 0; j < 4; ++j) acc[i][j] = MFMA16(av[i], bv[j], acc[i][j]);
    }
    __syncthreads();
  }

  if constexpr (MODE == 3) {
    float* C = (float*)Cv;
#pragma unroll
    for (int i = 0; i < 4; ++i)
#pragma unroll
      for (int r = 0; r < 4; ++r)
#pragma unroll
        for (int j = 0; j < 4; ++j) {
          int rowl = wr * 64 + i * 16 + blk * 4 + r;   // C layout: row=(lane>>4)*4+reg
          int coll = wc * 64 + j * 16 + r15;           //           col=lane&15
          C[(size_t)(m0 + rowl) * 2048 + n0 + coll] = acc[i][j][r];
        }
    return;
  } else if constexpr (MODE == 4) {
    // V^T: rowg=(h,d), col=(b,s); key s stored at pos (s&~15)|swap23(r15)
    unsigned short* Vtp = (unsigned short*)Cv;
    int p15 = (r15 & 3) | ((r15 & 4) << 1) | ((r15 & 8) >> 1);
#pragma unroll
    for (int i = 0; i < 4; ++i)
#pragma unroll
      for (int r = 0; r < 4; ++r) {
        int rowg = m0 + wr * 64 + i * 16 + blk * 4 + r;  // (h,d)
        int h = rowg >> 7, d = rowg & 127;
#pragma unroll
        for (int j = 0; j < 4; ++j) {
          int col = n0 + wc * 64 + j * 16;               // (b, s&~15)
          int b = col >> 11, s16 = col & 2047;
          Vtp[(((size_t)(b * 16 + h) * 128 + d) * 2048) + s16 + p15] = f2bf(acc[i][j][r]);
        }
      }
    return;
  } else {
    if constexpr (MODE == 1 || MODE == 2) {
      // per-row stats over the 128 cols (= head_dim) of this tile
#pragma unroll
      for (int i = 0; i < 4; ++i)
#pragma unroll
        for (int r = 0; r < 4; ++r) {
          float sm = 0.f, sq = 0.f;
#pragma unroll
          for (int j = 0; j < 4; ++j) { float v = acc[i][j][r]; sm += v; sq += v * v; }
          sm += __shfl_xor(sm, 1); sq += __shfl_xor(sq, 1);
          sm += __shfl_xor(sm, 2); sq += __shfl_xor(sq, 2);
          sm += __shfl_xor(sm, 4); sq += __shfl_xor(sq, 4);
          sm += __shfl_xor(sm, 8); sq += __shfl_xor(sq, 8);
          if (r15 == 0) {
            int rowl = wr * 64 + i * 16 + blk * 4 + r;
            sSum[wc][rowl] = sm; sSq[wc][rowl] = sq;
          }
        }
      __syncthreads();
    }
    unsigned short* Hout = (unsigned short*)Cv;
    int h = blockIdx.x;  // BN=128 == D: one head per n-block
#pragma unroll
    for (int i = 0; i < 4; ++i)
#pragma unroll
      for (int r = 0; r < 4; ++r) {
        int rowl = wr * 64 + i * 16 + blk * 4 + r;
        float mean = 0.f, rstd = 1.f;
        if constexpr (MODE == 1 || MODE == 2) {
          float sm = sSum[0][rowl] + sSum[1][rowl];
          float sq = sSq[0][rowl] + sSq[1][rowl];
          mean = sm * 0.0078125f;
          float var = sq * 0.0078125f - mean * mean;
          rstd = rsqrtf(var + 1e-6f);
        }
        int rowg = m0 + rowl;
        int b = rowg >> 11, s = rowg & 2047;
        unsigned short* orow = Hout + (((size_t)b * 16 + h) * 2048 + s) * 128;
#pragma unroll
        for (int j = 0; j < 4; ++j) {
          int d = wc * 64 + j * 16 + r15;
          float v = acc[i][j][r];
          // log2e folded in: attention softmax runs in exp2 domain
          if constexpr (MODE == 1)
            v = (v - mean) * rstd * lnsc[d] * (0.08838834764831845f * 1.4426950408889634f);
          if constexpr (MODE == 2) v = (v - mean) * rstd * lnsc[d];
          orow[d] = f2bf(v);
        }
      }
  }
}

// ---------------- flash attention v9: counted-vmcnt dbuf (T4) --------------
// 4 waves x 32 q = QBLK 128; KVBLK=64; dbuf 64 KB; grid 512 -> 2 blocks/CU.
// Per iter: issue stage(t+1) -> vmcnt(8) [stage(t) landed, t+1 in flight
// ACROSS the barrier] -> barrier -> compute(t) -> lgkmcnt(0) -> barrier.
__global__ __launch_bounds__(256, 2) void k_attn(const unsigned short* __restrict__ Qh,
                                                 const unsigned short* __restrict__ Kh,
                                                 const unsigned short* __restrict__ Vtp,
                                                 const unsigned* __restrict__ maskb,
                                                 unsigned short* __restrict__ O) {
  __shared__ __attribute__((aligned(16))) char smem[65536];  // 2 x (sK 16K + sV 16K)
  int tid = threadIdx.x, w = tid >> 6;
  int lane = tid & 63;
  int q31 = lane & 31, hi = lane >> 5;
  int bh = blockIdx.y, b = bh >> 4, h = bh & 15;
  int qb = blockIdx.x * 128;
  size_t base = (size_t)bh * (2048 * 128);
  int qrow = qb + w * 32 + q31;

  bf16x8 qf[8];  // Q (B-operand): col=q31, k-window wd: d = wd*16 + hi*8 + j
  {
    const unsigned short* qp = Qh + base + (size_t)qrow * 128 + hi * 8;
#pragma unroll
    for (int wd = 0; wd < 8; ++wd) qf[wd] = *(const bf16x8*)(qp + wd * 16);
  }
  const unsigned* mrow = maskb + ((size_t)b * 2048 + qrow) * 64;

  // staging bases (kc=0): K [64 keys][128 d] linear rows, V^T [128 d][64 pos]
  const unsigned short* kgp[4];
  const unsigned short* vgp[4];
#pragma unroll
  for (int i = 0; i < 4; ++i) {
    int c = i * 256 + tid;              // 0..1023 chunk id
    int rr = c >> 4, cc = c & 15;       // K: row rr, 16B chunk cc
    kgp[i] = Kh + base + (size_t)rr * 128 + ((cc ^ (rr & 15)) * 8);
    int d = c >> 3, c8 = c & 7;         // V: row d, chunk c8
    vgp[i] = Vtp + base + (size_t)d * 2048 + ((c8 ^ (d & 7)) * 8);
  }

  f32x16 o[4] = {};                     // o[dt]: col d = dt*32+q31, rows=q slots
  float mv = -1e30f, ls = 0.f;

  // prologue: stage tile 0 into buf 0 (8 VMEM ops/thread)
#pragma unroll
  for (int i = 0; i < 4; ++i) {
    int c = i * 256 + tid;
    gload_lds16(kgp[i], smem + c * 16);
    gload_lds16(vgp[i], smem + 16384 + c * 16);
  }

  int cur = 0;
  for (int kc = 0; kc < 2048; kc += 64) {
    if (kc + 64 < 2048) {  // issue stage(t+1) into the other buffer (8 ops)
      char* nb = smem + ((cur ^ 1) << 15);
#pragma unroll
      for (int i = 0; i < 4; ++i) {
        int c = i * 256 + tid;
        gload_lds16(kgp[i] + (size_t)(kc + 64) * 128, nb + c * 16);
        gload_lds16(vgp[i] + (kc + 64), nb + 16384 + c * 16);
      }
      // wait for everything OLDER than the 8 just-issued loads => stage(t) done
      asm volatile("s_waitcnt vmcnt(8)" ::: "memory");
    } else {
      asm volatile("s_waitcnt vmcnt(0)" ::: "memory");
    }
    __builtin_amdgcn_s_barrier();          // B1: buf[cur] ready on all lanes
    __builtin_amdgcn_sched_barrier(0);     // fence: no hoisting of ds_reads above
    const unsigned short* sK = (const unsigned short*)(smem + (cur << 15));
    const unsigned short* sV = (const unsigned short*)(smem + (cur << 15) + 16384);

    unsigned mw0 = mrow[kc >> 5] >> (4 * hi);
    unsigned mw1 = mrow[(kc >> 5) + 1] >> (4 * hi);

    // S^T: 2 key-tiles x 8 d-windows. A=K frag: row=key=q31 (lane pos), k-window wd
    f32x16 st0 = {}, st1 = {};
    __builtin_amdgcn_s_setprio(1);
#pragma unroll
    for (int wd = 0; wd < 8; ++wd) {
      int ck = ((2 * wd + hi) ^ (q31 & 15)) * 8;
      bf16x8 k0 = *(const bf16x8*)&sK[q31 * 128 + ck];
      bf16x8 k1 = *(const bf16x8*)&sK[(32 + q31) * 128 + ck];
      st0 = MFMA32(k0, qf[wd], st0);
      st1 = MFMA32(k1, qf[wd], st1);
    }
    __builtin_amdgcn_s_setprio(0);

    // mask: slot r of tile kt = key kt*32 + (r&3)+8*(r>>2)+4*hi
    float pvv[32];
#pragma unroll
    for (int r = 0; r < 16; ++r) {
      int bit = (r & 3) + 8 * (r >> 2);  // compile-time
      pvv[r] = ((mw0 >> bit) & 1u) ? st0[r] : -1e30f;
      pvv[16 + r] = ((mw1 >> bit) & 1u) ? st1[r] : -1e30f;
    }
    // max over 32 slots (tree)
    float c0 = max3f(pvv[0], pvv[1], pvv[2]);
    float c1 = max3f(pvv[3], pvv[4], pvv[5]);
    float c2 = max3f(pvv[6], pvv[7], pvv[8]);
    float c3 = max3f(pvv[9], pvv[10], pvv[11]);
    float c4 = max3f(pvv[12], pvv[13], pvv[14]);
    float c5 = max3f(pvv[15], pvv[16], pvv[17]);
    float c6 = max3f(pvv[18], pvv[19], pvv[20]);
    float c7 = max3f(pvv[21], pvv[22], pvv[23]);
    float c8 = max3f(pvv[24], pvv[25], pvv[26]);
    float c9 = max3f(pvv[27], pvv[28], pvv[29]);
    float ca = fmaxf(pvv[30], pvv[31]);
    float t0 = max3f(c0, c1, c2);
    float t1 = max3f(c3, c4, c5);
    float t2 = max3f(c6, c7, c8);
    float t3 = max3f(c9, ca, t0);
    float cmax = max3f(t1, t2, t3);
    cmax = fmaxf(cmax, __shfl_xor(cmax, 32));

    if (!__all(cmax - mv <= 11.5f)) {  // defer-max: P bounded by 2^11.5
      float mnew = fmaxf(mv, cmax);
      float fac = exp2a(mv - mnew);
      ls *= fac;
      float fr[16];
#pragma unroll
      for (int r = 0; r < 16; ++r) fr[r] = __shfl(fac, (r & 3) + 8 * (r >> 2) + 4 * hi);
#pragma unroll
      for (int dt = 0; dt < 4; ++dt)
#pragma unroll
        for (int r = 0; r < 16; ++r) o[dt][r] *= fr[r];
      mv = mnew;
    }

#pragma unroll
    for (int t = 0; t < 32; ++t) pvv[t] = exp2a(pvv[t] - mv);
    {
      float s0 = 0.f, s1 = 0.f, s2 = 0.f, s3 = 0.f;
#pragma unroll
      for (int t = 0; t < 8; ++t) {
        s0 += pvv[t]; s1 += pvv[8 + t]; s2 += pvv[16 + t]; s3 += pvv[24 + t];
      }
      ls += (s0 + s1) + (s2 + s3);
    }

    // packs: window kw covers pvv[8*kw .. 8*kw+7] (= keys kw*16 + sigma(hi,j))
    bf16x8 pa[4];
#pragma unroll
    for (int kw = 0; kw < 4; ++kw) {
      uint4v pw;
#pragma unroll
      for (int m = 0; m < 4; ++m) pw[m] = pkbf(pvv[8 * kw + 2 * m], pvv[8 * kw + 2 * m + 1]);
      pa[kw] = __builtin_bit_cast(bf16x8, pw);
    }

    // PV: o[dt] += P(window kw) x V; B-frag = sV row dt*32+q31, chunk (2kw+hi)
    __builtin_amdgcn_s_setprio(1);
#pragma unroll
    for (int dt = 0; dt < 4; ++dt) {
      int vrow = dt * 32 + q31;
#pragma unroll
      for (int kw = 0; kw < 4; ++kw) {
        int cv = ((2 * kw + hi) ^ (q31 & 7)) * 8;
        bf16x8 vf = *(const bf16x8*)&sV[vrow * 64 + cv];
        o[dt] = MFMA32(pa[kw], vf, o[dt]);
      }
    }
    __builtin_amdgcn_s_setprio(0);
    asm volatile("s_waitcnt lgkmcnt(0)" ::: "memory");  // all LDS reads done
    __builtin_amdgcn_s_barrier();          // B2: buffer safe to overwrite
    cur ^= 1;
  }

  // normalize factors: partner lane (l^32) holds the other half of the keys
  ls += __shfl_xor(ls, 32);
  float inv = 1.f / ls;
  float ir[16];
#pragma unroll
  for (int r = 0; r < 16; ++r) ir[r] = __shfl(inv, (r & 3) + 8 * (r >> 2) + 4 * hi);

  // epilogue: two 64-row passes through sO overlay (waves 0-1, then 2-3)
  float* sO = (float*)smem;
#pragma unroll
  for (int pass = 0; pass < 2; ++pass) {
    __syncthreads();
    if ((w >> 1) == pass) {
      int wl = w & 1;
#pragma unroll
      for (int dt = 0; dt < 4; ++dt)
#pragma unroll
        for (int r = 0; r < 16; ++r) {
          int qrl = wl * 32 + (r & 3) + 8 * (r >> 2) + 4 * hi;
          sO[qrl * 132 + dt * 32 + q31] = o[dt][r] * ir[r];
        }
    }
    __syncthreads();
    {
      int row = tid >> 2, d0 = (tid & 3) * 32;
      int grow = qb + pass * 64 + row;
      unsigned short* op = O + (size_t)(b * 2048 + grow) * 2048 + h * 128 + d0;
#pragma unroll
      for (int g = 0; g < 4; ++g) {
        ushort8 pk;
#pragma unroll
        for (int e = 0; e < 8; ++e) pk[e] = f2bf(sO[row * 132 + d0 + g * 8 + e]);
        *(ushort8*)(op + g * 8) = pk;
      }
    }
  }
}

// ---------------------------------------------------------------------------
extern "C" void kernel_launch(void* const* d_in, const int* in_sizes, int n_in,
                              void* d_out, int out_size, void* d_ws, size_t ws_size,
                              hipStream_t stream) {
  const float* q      = (const float*)d_in[0];
  const float* kv     = (const float*)d_in[1];
  const float* q_pos  = (const float*)d_in[2];
  const float* kv_pos = (const float*)d_in[3];
  const int*   mask   = (const int*)d_in[4];
  const float* wq     = (const float*)d_in[5];
  const float* wk     = (const float*)d_in[6];
  const float* wv     = (const float*)d_in[7];
  const float* qls    = (const float*)d_in[8];
  const float* kls    = (const float*)d_in[9];
  const float* wo     = (const float*)d_in[10];

  char* ws = (char*)d_ws;
  const size_t SZ_ACT = (size_t)4096 * 2048 * 2;  // 16 MiB
  const size_t SZ_W   = (size_t)2048 * 2048 * 2;  // 8 MiB
  unsigned short* a_q = (unsigned short*)(ws);
  unsigned short* a_k = (unsigned short*)(ws + SZ_ACT);
  unsigned short* a_v = (unsigned short*)(ws + 2 * SZ_ACT);
  unsigned short* Qh  = (unsigned short*)(ws + 3 * SZ_ACT);
  unsigned short* Kh  = (unsigned short*)(ws + 4 * SZ_ACT);
  unsigned short* wqt = (unsigned short*)(ws + 6 * SZ_ACT);
  unsigned short* wkt = (unsigned short*)(ws + 6 * SZ_ACT + SZ_W);
  unsigned short* wvt = (unsigned short*)(ws + 6 * SZ_ACT + 2 * SZ_W);
  unsigned short* wot = (unsigned short*)(ws + 6 * SZ_ACT + 3 * SZ_W);
  unsigned*       mkb = (unsigned*)(ws + 6 * SZ_ACT + 4 * SZ_W);
  unsigned short* Ob  = a_q;  // a_q dead after Q-projection; reuse for attn out
  unsigned short* Vtr = (unsigned short*)(ws + 5 * SZ_ACT);  // V^T (direct from MODE 4)

  const size_t NEED = 6 * SZ_ACT + 4 * SZ_W + (size_t)2 * 2048 * 64 * 4;
  if (ws_size < NEED) return;  // leave d_out poisoned -> visible failure

  k_cvt<<<8192, 256, 0, stream>>>((const float4v*)q, (const float4v*)q_pos, (ushort4v*)a_q, 2097152);
  k_cvt2<<<8192, 256, 0, stream>>>((const float4v*)kv, (const float4v*)kv_pos,
                                   (ushort4v*)a_k, (ushort4v*)a_v, 2097152);
  k_tr<<<dim3(64, 64, 4), 256, 0, stream>>>(wq, wk, wv, wo, wqt, wkt, wvt, wot);
  k_mask<<<32768, 256, 0, stream>>>(mask, (unsigned long long*)mkb);

  k_gemm<1><<<dim3(16, 32), 256, 0, stream>>>(a_q, wqt, Qh, qls);
  k_gemm<2><<<dim3(16, 32), 256, 0, stream>>>(a_k, wkt, Kh, kls);
  // V^T directly: A=wvt (M=2048 rows=(h,d)), Bt=a_v (N=4096 cols=(b,s))
  k_gemm<4><<<dim3(32, 16), 256, 0, stream>>>(wvt, a_v, Vtr, nullptr);

  k_attn<<<dim3(16, 32), 256, 0, stream>>>(Qh, Kh, Vtr, mkb, Ob);

  k_gemm<3><<<dim3(16, 32), 256, 0, stream>>>(Ob, wot, d_out, nullptr);
}

// Round 11
// 341.460 us; speedup vs baseline: 1.0039x; 1.0039x over previous
//
#include <hip/hip_runtime.h>
#include <hip/hip_bf16.h>

// ---------------------------------------------------------------------------
// AttentionBlock: qkv-proj (+LN on q,k) -> masked flash attention -> out-proj
// B=2, S=2048, E=2048, H=16, D=128. GEMMs: bf16 MFMA 16x16x32 (m97 structure).
// Attention: bf16 MFMA 32x32x16, swapped QK^T (4-way split accumulation
// chains), exp2-domain softmax, single-barrier dbuf (issue-early staging).
// V^T produced directly by a swapped-operand GEMM (MODE 4) with the
// key-position permutation baked into the store.
// ---------------------------------------------------------------------------

typedef __attribute__((ext_vector_type(8))) __bf16 bf16x8;
typedef __attribute__((ext_vector_type(4))) float f32x4;
typedef __attribute__((ext_vector_type(16))) float f32x16;
typedef __attribute__((ext_vector_type(8))) unsigned short ushort8;
typedef __attribute__((ext_vector_type(4))) unsigned short ushort4v;
typedef __attribute__((ext_vector_type(4))) unsigned uint4v;
typedef __attribute__((ext_vector_type(4))) float float4v;

#define MFMA16(a, b, c) __builtin_amdgcn_mfma_f32_16x16x32_bf16((a), (b), (c), 0, 0, 0)
#define MFMA32(a, b, c) __builtin_amdgcn_mfma_f32_32x32x16_bf16((a), (b), (c), 0, 0, 0)

__device__ __forceinline__ unsigned short f2bf(float f) {
  unsigned u = __builtin_bit_cast(unsigned, f);
  u += 0x7fffu + ((u >> 16) & 1u);           // RNE
  return (unsigned short)(u >> 16);
}

__device__ __forceinline__ unsigned pkbf(float lo, float hi) {  // bf16(lo)|bf16(hi)<<16
  unsigned d;
  asm("v_cvt_pk_bf16_f32 %0, %1, %2" : "=v"(d) : "v"(lo), "v"(hi));
  return d;
}

__device__ __forceinline__ float max3f(float a, float b, float c) {
  float d;
  asm("v_max3_f32 %0, %1, %2, %3" : "=v"(d) : "v"(a), "v"(b), "v"(c));
  return d;
}

__device__ __forceinline__ float exp2a(float x) {  // 2^x
  float d;
  asm("v_exp_f32 %0, %1" : "=v"(d) : "v"(x));
  return d;
}

__device__ __forceinline__ void gload_lds16(const void* g, void* l) {
  __builtin_amdgcn_global_load_lds(
      (const __attribute__((address_space(1))) void*)g,
      (__attribute__((address_space(3))) void*)l, 16, 0, 0);
}

// ---------------- prep: elementwise add + fp32->bf16 -----------------------
__global__ __launch_bounds__(256) void k_cvt(const float4v* __restrict__ x,
                                             const float4v* __restrict__ y,
                                             ushort4v* __restrict__ o, int n4) {
  int i = blockIdx.x * 256 + threadIdx.x;
  if (i >= n4) return;
  float4v a = x[i];
  if (y) { float4v b = y[i]; a = a + b; }
  ushort4v r;
  r[0] = f2bf(a[0]); r[1] = f2bf(a[1]); r[2] = f2bf(a[2]); r[3] = f2bf(a[3]);
  o[i] = r;
}

// ---------------- prep: kv -> a_k (kv+kv_pos) and a_v (kv) in one pass -----
__global__ __launch_bounds__(256) void k_cvt2(const float4v* __restrict__ x,
                                              const float4v* __restrict__ y,
                                              ushort4v* __restrict__ oa,
                                              ushort4v* __restrict__ ob, int n4) {
  int i = blockIdx.x * 256 + threadIdx.x;
  if (i >= n4) return;
  float4v a = x[i];
  float4v s = a + y[i];
  ushort4v ra, rb;
  ra[0] = f2bf(s[0]); ra[1] = f2bf(s[1]); ra[2] = f2bf(s[2]); ra[3] = f2bf(s[3]);
  rb[0] = f2bf(a[0]); rb[1] = f2bf(a[1]); rb[2] = f2bf(a[2]); rb[3] = f2bf(a[3]);
  oa[i] = ra; ob[i] = rb;
}

// ---------------- prep: weight transpose fp32[K][N] -> bf16[N][K] ----------
__global__ __launch_bounds__(256) void k_tr(const float* __restrict__ s0, const float* __restrict__ s1,
                                            const float* __restrict__ s2, const float* __restrict__ s3,
                                            unsigned short* __restrict__ d0, unsigned short* __restrict__ d1,
                                            unsigned short* __restrict__ d2, unsigned short* __restrict__ d3) {
  __shared__ float t[32][33];
  const float* S; unsigned short* D;
  switch (blockIdx.z) {
    case 0: S = s0; D = d0; break;
    case 1: S = s1; D = d1; break;
    case 2: S = s2; D = d2; break;
    default: S = s3; D = d3; break;
  }
  int x = threadIdx.x & 31, y = threadIdx.x >> 5;
  int r0 = blockIdx.y * 32, c0 = blockIdx.x * 32;
#pragma unroll
  for (int i = 0; i < 4; ++i) t[y + 8 * i][x] = S[(size_t)(r0 + y + 8 * i) * 2048 + c0 + x];
  __syncthreads();
#pragma unroll
  for (int i = 0; i < 4; ++i)
    D[(size_t)(c0 + y + 8 * i) * 2048 + r0 + x] = f2bf(t[x][y + 8 * i]);
}

// ---------------- prep: mask int32 -> bitmask (1 bit/key) ------------------
__global__ __launch_bounds__(256) void k_mask(const int* __restrict__ m,
                                              unsigned long long* __restrict__ out) {
  int i = blockIdx.x * 256 + threadIdx.x;
  unsigned long long b = __ballot(m[i] != 0);
  if ((threadIdx.x & 63) == 0) out[i >> 6] = b;
}

// ---------------- GEMM 128x128 tile, BK=64, 4 waves (m97 structure) --------
// MODE 1: LN*scale*rsqrt(D)*log2e (Q) -> [B,H,S,D] bf16
// MODE 2: LN*scale (K)               -> [B,H,S,D] bf16
// MODE 3: fp32 direct to [4096][2048] (final out-proj)
// MODE 4: V^T direct: A=wvt (M=2048=(h,d)), Bt=a_v (N=4096=(b,s));
//         store at Vtp[bh][d][(s&~15)|swap23(s&15)] bf16.
template <int MODE>
__global__ __launch_bounds__(256) void k_gemm(const unsigned short* __restrict__ A,
                                              const unsigned short* __restrict__ Bt,
                                              void* __restrict__ Cv,
                                              const float* __restrict__ lnsc) {
  constexpr int K = 2048;
  __shared__ __attribute__((aligned(16))) unsigned short sA[128 * 64];
  __shared__ __attribute__((aligned(16))) unsigned short sB[128 * 64];
  __shared__ float sSum[2][128];
  __shared__ float sSq[2][128];
  int tid = threadIdx.x;
  int lane = tid & 63, w = tid >> 6;
  int wr = w >> 1, wc = w & 1;
  int r15 = lane & 15, blk = lane >> 4;
  int n0 = blockIdx.x * 128, m0 = blockIdx.y * 128;
  const unsigned short* Abase = A + (size_t)m0 * K;
  const unsigned short* Bbase = Bt + (size_t)n0 * K;
  f32x4 acc[4][4] = {};

  for (int kt = 0; kt < K; kt += 64) {
#pragma unroll
    for (int i = 0; i < 4; ++i) {   // stage A tile: 1024 16B chunks, XOR-swizzled source
      int c = i * 256 + tid;
      int row = c >> 3, cc = c & 7;
      gload_lds16(Abase + (size_t)row * K + kt + ((cc ^ (row & 7)) * 8), &sA[c * 8]);
    }
#pragma unroll
    for (int i = 0; i < 4; ++i) {   // stage B tile
      int c = i * 256 + tid;
      int row = c >> 3, cc = c & 7;
      gload_lds16(Bbase + (size_t)row * K + kt + ((cc ^ (row & 7)) * 8), &sB[c * 8]);
    }
    __syncthreads();
#pragma unroll
    for (int kk = 0; kk < 2; ++kk) {
      bf16x8 av[4], bv[4];
#pragma unroll
      for (int i = 0; i < 4; ++i) {
        int row = wr * 64 + i * 16 + r15;
        av[i] = *(const bf16x8*)&sA[row * 64 + (((kk * 4 + blk) ^ (row & 7)) * 8)];
      }
#pragma unroll
      for (int j = 0; j < 4; ++j) {
        int row = wc * 64 + j * 16 + r15;
        bv[j] = *(const bf16x8*)&sB[row * 64 + (((kk * 4 + blk) ^ (row & 7)) * 8)];
      }
#pragma unroll
      for (int i = 0; i < 4; ++i)
#pragma unroll
        for (int j = 0; j < 4; ++j) acc[i][j] = MFMA16(av[i], bv[j], acc[i][j]);
    }
    __syncthreads();
  }

  if constexpr (MODE == 3) {
    float* C = (float*)Cv;
#pragma unroll
    for (int i = 0; i < 4; ++i)
#pragma unroll
      for (int r = 0; r < 4; ++r)
#pragma unroll
        for (int j = 0; j < 4; ++j) {
          int rowl = wr * 64 + i * 16 + blk * 4 + r;   // C layout: row=(lane>>4)*4+reg
          int coll = wc * 64 + j * 16 + r15;           //           col=lane&15
          C[(size_t)(m0 + rowl) * 2048 + n0 + coll] = acc[i][j][r];
        }
    return;
  } else if constexpr (MODE == 4) {
    // V^T: rowg=(h,d), col=(b,s); key s stored at pos (s&~15)|swap23(r15)
    unsigned short* Vtp = (unsigned short*)Cv;
    int p15 = (r15 & 3) | ((r15 & 4) << 1) | ((r15 & 8) >> 1);
#pragma unroll
    for (int i = 0; i < 4; ++i)
#pragma unroll
      for (int r = 0; r < 4; ++r) {
        int rowg = m0 + wr * 64 + i * 16 + blk * 4 + r;  // (h,d)
        int h = rowg >> 7, d = rowg & 127;
#pragma unroll
        for (int j = 0; j < 4; ++j) {
          int col = n0 + wc * 64 + j * 16;               // (b, s&~15)
          int b = col >> 11, s16 = col & 2047;
          Vtp[(((size_t)(b * 16 + h) * 128 + d) * 2048) + s16 + p15] = f2bf(acc[i][j][r]);
        }
      }
    return;
  } else {
    if constexpr (MODE == 1 || MODE == 2) {
      // per-row stats over the 128 cols (= head_dim) of this tile
#pragma unroll
      for (int i = 0; i < 4; ++i)
#pragma unroll
        for (int r = 0; r < 4; ++r) {
          float sm = 0.f, sq = 0.f;
#pragma unroll
          for (int j = 0; j < 4; ++j) { float v = acc[i][j][r]; sm += v; sq += v * v; }
          sm += __shfl_xor(sm, 1); sq += __shfl_xor(sq, 1);
          sm += __shfl_xor(sm, 2); sq += __shfl_xor(sq, 2);
          sm += __shfl_xor(sm, 4); sq += __shfl_xor(sq, 4);
          sm += __shfl_xor(sm, 8); sq += __shfl_xor(sq, 8);
          if (r15 == 0) {
            int rowl = wr * 64 + i * 16 + blk * 4 + r;
            sSum[wc][rowl] = sm; sSq[wc][rowl] = sq;
          }
        }
      __syncthreads();
    }
    unsigned short* Hout = (unsigned short*)Cv;
    int h = blockIdx.x;  // BN=128 == D: one head per n-block
#pragma unroll
    for (int i = 0; i < 4; ++i)
#pragma unroll
      for (int r = 0; r < 4; ++r) {
        int rowl = wr * 64 + i * 16 + blk * 4 + r;
        float mean = 0.f, rstd = 1.f;
        if constexpr (MODE == 1 || MODE == 2) {
          float sm = sSum[0][rowl] + sSum[1][rowl];
          float sq = sSq[0][rowl] + sSq[1][rowl];
          mean = sm * 0.0078125f;
          float var = sq * 0.0078125f - mean * mean;
          rstd = rsqrtf(var + 1e-6f);
        }
        int rowg = m0 + rowl;
        int b = rowg >> 11, s = rowg & 2047;
        unsigned short* orow = Hout + (((size_t)b * 16 + h) * 2048 + s) * 128;
#pragma unroll
        for (int j = 0; j < 4; ++j) {
          int d = wc * 64 + j * 16 + r15;
          float v = acc[i][j][r];
          // log2e folded in: attention softmax runs in exp2 domain
          if constexpr (MODE == 1)
            v = (v - mean) * rstd * lnsc[d] * (0.08838834764831845f * 1.4426950408889634f);
          if constexpr (MODE == 2) v = (v - mean) * rstd * lnsc[d];
          orow[d] = f2bf(v);
        }
      }
  }
}

// ---------------- flash attention v10: 4-way QK chain split ----------------
// 4 waves x 32 q = QBLK 128; KVBLK=64; dbuf 64 KB; grid 512 -> 2 blocks/CU.
// Single barrier per iter (r8 schedule: issue-early staging, barrier drains
// loads issued a full compute-phase earlier). QK^T uses 4 independent
// accumulation chains (depth 4) instead of 2 (depth 8) for MFMA latency ILP.
__global__ __launch_bounds__(256, 2) void k_attn(const unsigned short* __restrict__ Qh,
                                                 const unsigned short* __restrict__ Kh,
                                                 const unsigned short* __restrict__ Vtp,
                                                 const unsigned* __restrict__ maskb,
                                                 unsigned short* __restrict__ O) {
  __shared__ __attribute__((aligned(16))) char smem[65536];  // 2 x (sK 16K + sV 16K)
  int tid = threadIdx.x, w = tid >> 6;
  int lane = tid & 63;
  int q31 = lane & 31, hi = lane >> 5;
  int bh = blockIdx.y, b = bh >> 4, h = bh & 15;
  int qb = blockIdx.x * 128;
  size_t base = (size_t)bh * (2048 * 128);
  int qrow = qb + w * 32 + q31;

  bf16x8 qf[8];  // Q (B-operand): col=q31, k-window wd: d = wd*16 + hi*8 + j
  {
    const unsigned short* qp = Qh + base + (size_t)qrow * 128 + hi * 8;
#pragma unroll
    for (int wd = 0; wd < 8; ++wd) qf[wd] = *(const bf16x8*)(qp + wd * 16);
  }
  const unsigned* mrow = maskb + ((size_t)b * 2048 + qrow) * 64;

  // staging bases (kc=0): K [64 keys][128 d] linear rows, V^T [128 d][64 pos]
  const unsigned short* kgp[4];
  const unsigned short* vgp[4];
#pragma unroll
  for (int i = 0; i < 4; ++i) {
    int c = i * 256 + tid;              // 0..1023 chunk id
    int rr = c >> 4, cc = c & 15;       // K: row rr, 16B chunk cc
    kgp[i] = Kh + base + (size_t)rr * 128 + ((cc ^ (rr & 15)) * 8);
    int d = c >> 3, c8 = c & 7;         // V: row d, chunk c8
    vgp[i] = Vtp + base + (size_t)d * 2048 + ((c8 ^ (d & 7)) * 8);
  }

  f32x16 o[4] = {};                     // o[dt]: col d = dt*32+q31, rows=q slots
  float mv = -1e30f, ls = 0.f;

  // prologue: stage tile 0 into buf 0
#pragma unroll
  for (int i = 0; i < 4; ++i) {
    int c = i * 256 + tid;
    gload_lds16(kgp[i], smem + c * 16);
    gload_lds16(vgp[i], smem + 16384 + c * 16);
  }
  __syncthreads();

  int cur = 0;
  for (int kc = 0; kc < 2048; kc += 64) {
    if (kc + 64 < 2048) {  // issue stage(t+1) early; drained by iter-end barrier
      char* nb = smem + ((cur ^ 1) << 15);
#pragma unroll
      for (int i = 0; i < 4; ++i) {
        int c = i * 256 + tid;
        gload_lds16(kgp[i] + (size_t)(kc + 64) * 128, nb + c * 16);
        gload_lds16(vgp[i] + (kc + 64), nb + 16384 + c * 16);
      }
    }
    const unsigned short* sK = (const unsigned short*)(smem + (cur << 15));
    const unsigned short* sV = (const unsigned short*)(smem + (cur << 15) + 16384);

    unsigned mw0 = mrow[kc >> 5] >> (4 * hi);
    unsigned mw1 = mrow[(kc >> 5) + 1] >> (4 * hi);

    // S^T: 2 key-tiles x 8 d-windows, split into 4 independent chains (depth 4)
    f32x16 st0a = {}, st0b = {}, st1a = {}, st1b = {};
#pragma unroll
    for (int wd = 0; wd < 4; ++wd) {
      int ckA = ((2 * wd + hi) ^ (q31 & 15)) * 8;
      int ckB = ((2 * (wd + 4) + hi) ^ (q31 & 15)) * 8;
      bf16x8 k0a = *(const bf16x8*)&sK[q31 * 128 + ckA];
      bf16x8 k1a = *(const bf16x8*)&sK[(32 + q31) * 128 + ckA];
      bf16x8 k0b = *(const bf16x8*)&sK[q31 * 128 + ckB];
      bf16x8 k1b = *(const bf16x8*)&sK[(32 + q31) * 128 + ckB];
      st0a = MFMA32(k0a, qf[wd], st0a);
      st1a = MFMA32(k1a, qf[wd], st1a);
      st0b = MFMA32(k0b, qf[wd + 4], st0b);
      st1b = MFMA32(k1b, qf[wd + 4], st1b);
    }
    f32x16 st0 = st0a + st0b;
    f32x16 st1 = st1a + st1b;

    // mask: slot r of tile kt = key kt*32 + (r&3)+8*(r>>2)+4*hi
    float pvv[32];
#pragma unroll
    for (int r = 0; r < 16; ++r) {
      int bit = (r & 3) + 8 * (r >> 2);  // compile-time
      pvv[r] = ((mw0 >> bit) & 1u) ? st0[r] : -1e30f;
      pvv[16 + r] = ((mw1 >> bit) & 1u) ? st1[r] : -1e30f;
    }
    // max over 32 slots (tree)
    float c0 = max3f(pvv[0], pvv[1], pvv[2]);
    float c1 = max3f(pvv[3], pvv[4], pvv[5]);
    float c2 = max3f(pvv[6], pvv[7], pvv[8]);
    float c3 = max3f(pvv[9], pvv[10], pvv[11]);
    float c4 = max3f(pvv[12], pvv[13], pvv[14]);
    float c5 = max3f(pvv[15], pvv[16], pvv[17]);
    float c6 = max3f(pvv[18], pvv[19], pvv[20]);
    float c7 = max3f(pvv[21], pvv[22], pvv[23]);
    float c8 = max3f(pvv[24], pvv[25], pvv[26]);
    float c9 = max3f(pvv[27], pvv[28], pvv[29]);
    float ca = fmaxf(pvv[30], pvv[31]);
    float t0 = max3f(c0, c1, c2);
    float t1 = max3f(c3, c4, c5);
    float t2 = max3f(c6, c7, c8);
    float t3 = max3f(c9, ca, t0);
    float cmax = max3f(t1, t2, t3);
    cmax = fmaxf(cmax, __shfl_xor(cmax, 32));

    if (!__all(cmax - mv <= 11.5f)) {  // defer-max: P bounded by 2^11.5
      float mnew = fmaxf(mv, cmax);
      float fac = exp2a(mv - mnew);
      ls *= fac;
      float fr[16];
#pragma unroll
      for (int r = 0; r < 16; ++r) fr[r] = __shfl(fac, (r & 3) + 8 * (r >> 2) + 4 * hi);
#pragma unroll
      for (int dt = 0; dt < 4; ++dt)
#pragma unroll
        for (int r = 0; r < 16; ++r) o[dt][r] *= fr[r];
      mv = mnew;
    }

#pragma unroll
    for (int t = 0; t < 32; ++t) pvv[t] = exp2a(pvv[t] - mv);
    {
      float s0 = 0.f, s1 = 0.f, s2 = 0.f, s3 = 0.f;
#pragma unroll
      for (int t = 0; t < 8; ++t) {
        s0 += pvv[t]; s1 += pvv[8 + t]; s2 += pvv[16 + t]; s3 += pvv[24 + t];
      }
      ls += (s0 + s1) + (s2 + s3);
    }

    // packs: window kw covers pvv[8*kw .. 8*kw+7] (= keys kw*16 + sigma(hi,j))
    bf16x8 pa[4];
#pragma unroll
    for (int kw = 0; kw < 4; ++kw) {
      uint4v pw;
#pragma unroll
      for (int m = 0; m < 4; ++m) pw[m] = pkbf(pvv[8 * kw + 2 * m], pvv[8 * kw + 2 * m + 1]);
      pa[kw] = __builtin_bit_cast(bf16x8, pw);
    }

    // PV: o[dt] += P(window kw) x V; B-frag = sV row dt*32+q31, chunk (2kw+hi)
#pragma unroll
    for (int dt = 0; dt < 4; ++dt) {
      int vrow = dt * 32 + q31;
#pragma unroll
      for (int kw = 0; kw < 4; ++kw) {
        int cv = ((2 * kw + hi) ^ (q31 & 7)) * 8;
        bf16x8 vf = *(const bf16x8*)&sV[vrow * 64 + cv];
        o[dt] = MFMA32(pa[kw], vf, o[dt]);
      }
    }
    __syncthreads();
    cur ^= 1;
  }

  // normalize factors: partner lane (l^32) holds the other half of the keys
  ls += __shfl_xor(ls, 32);
  float inv = 1.f / ls;
  float ir[16];
#pragma unroll
  for (int r = 0; r < 16; ++r) ir[r] = __shfl(inv, (r & 3) + 8 * (r >> 2) + 4 * hi);

  // epilogue: two 64-row passes through sO overlay (waves 0-1, then 2-3)
  float* sO = (float*)smem;
#pragma unroll
  for (int pass = 0; pass < 2; ++pass) {
    __syncthreads();
    if ((w >> 1) == pass) {
      int wl = w & 1;
#pragma unroll
      for (int dt = 0; dt < 4; ++dt)
#pragma unroll
        for (int r = 0; r < 16; ++r) {
          int qrl = wl * 32 + (r & 3) + 8 * (r >> 2) + 4 * hi;
          sO[qrl * 132 + dt * 32 + q31] = o[dt][r] * ir[r];
        }
    }
    __syncthreads();
    {
      int row = tid >> 2, d0 = (tid & 3) * 32;
      int grow = qb + pass * 64 + row;
      unsigned short* op = O + (size_t)(b * 2048 + grow) * 2048 + h * 128 + d0;
#pragma unroll
      for (int g = 0; g < 4; ++g) {
        ushort8 pk;
#pragma unroll
        for (int e = 0; e < 8; ++e) pk[e] = f2bf(sO[row * 132 + d0 + g * 8 + e]);
        *(ushort8*)(op + g * 8) = pk;
      }
    }
  }
}

// ---------------------------------------------------------------------------
extern "C" void kernel_launch(void* const* d_in, const int* in_sizes, int n_in,
                              void* d_out, int out_size, void* d_ws, size_t ws_size,
                              hipStream_t stream) {
  const float* q      = (const float*)d_in[0];
  const float* kv     = (const float*)d_in[1];
  const float* q_pos  = (const float*)d_in[2];
  const float* kv_pos = (const float*)d_in[3];
  const int*   mask   = (const int*)d_in[4];
  const float* wq     = (const float*)d_in[5];
  const float* wk     = (const float*)d_in[6];
  const float* wv     = (const float*)d_in[7];
  const float* qls    = (const float*)d_in[8];
  const float* kls    = (const float*)d_in[9];
  const float* wo     = (const float*)d_in[10];

  char* ws = (char*)d_ws;
  const size_t SZ_ACT = (size_t)4096 * 2048 * 2;  // 16 MiB
  const size_t SZ_W   = (size_t)2048 * 2048 * 2;  // 8 MiB
  unsigned short* a_q = (unsigned short*)(ws);
  unsigned short* a_k = (unsigned short*)(ws + SZ_ACT);
  unsigned short* a_v = (unsigned short*)(ws + 2 * SZ_ACT);
  unsigned short* Qh  = (unsigned short*)(ws + 3 * SZ_ACT);
  unsigned short* Kh  = (unsigned short*)(ws + 4 * SZ_ACT);
  unsigned short* wqt = (unsigned short*)(ws + 6 * SZ_ACT);
  unsigned short* wkt = (unsigned short*)(ws + 6 * SZ_ACT + SZ_W);
  unsigned short* wvt = (unsigned short*)(ws + 6 * SZ_ACT + 2 * SZ_W);
  unsigned short* wot = (unsigned short*)(ws + 6 * SZ_ACT + 3 * SZ_W);
  unsigned*       mkb = (unsigned*)(ws + 6 * SZ_ACT + 4 * SZ_W);
  unsigned short* Ob  = a_q;  // a_q dead after Q-projection; reuse for attn out
  unsigned short* Vtr = (unsigned short*)(ws + 5 * SZ_ACT);  // V^T (direct from MODE 4)

  const size_t NEED = 6 * SZ_ACT + 4 * SZ_W + (size_t)2 * 2048 * 64 * 4;
  if (ws_size < NEED) return;  // leave d_out poisoned -> visible failure

  k_cvt<<<8192, 256, 0, stream>>>((const float4v*)q, (const float4v*)q_pos, (ushort4v*)a_q, 2097152);
  k_cvt2<<<8192, 256, 0, stream>>>((const float4v*)kv, (const float4v*)kv_pos,
                                   (ushort4v*)a_k, (ushort4v*)a_v, 2097152);
  k_tr<<<dim3(64, 64, 4), 256, 0, stream>>>(wq, wk, wv, wo, wqt, wkt, wvt, wot);
  k_mask<<<32768, 256, 0, stream>>>(mask, (unsigned long long*)mkb);

  k_gemm<1><<<dim3(16, 32), 256, 0, stream>>>(a_q, wqt, Qh, qls);
  k_gemm<2><<<dim3(16, 32), 256, 0, stream>>>(a_k, wkt, Kh, kls);
  // V^T directly: A=wvt (M=2048 rows=(h,d)), Bt=a_v (N=4096 cols=(b,s))
  k_gemm<4><<<dim3(32, 16), 256, 0, stream>>>(wvt, a_v, Vtr, nullptr);

  k_attn<<<dim3(16, 32), 256, 0, stream>>>(Qh, Kh, Vtr, mkb, Ob);

  k_gemm<3><<<dim3(16, 32), 256, 0, stream>>>(Ob, wot, d_out, nullptr);
}

// Round 12
// 326.135 us; speedup vs baseline: 1.0511x; 1.0470x over previous
//
#include <hip/hip_runtime.h>
#include <hip/hip_bf16.h>

// ---------------------------------------------------------------------------
// AttentionBlock: qkv-proj (+LN on q,k) -> masked flash attention -> out-proj
// B=2, S=2048, E=2048, H=16, D=128.
// GEMMs: NEW tri-buffered counted-vmcnt pipeline (256x128 tile, BK=64,
// 8 waves, 3 LDS buffers, vmcnt(6) mid-loop - loads in flight across barriers).
// Attention: bf16 MFMA 32x32x16, swapped QK^T, exp2-domain softmax (r9 best).
// V^T produced directly by swapped-operand GEMM (MODE 4, key-perm store).
// ---------------------------------------------------------------------------

typedef __attribute__((ext_vector_type(8))) __bf16 bf16x8;
typedef __attribute__((ext_vector_type(4))) float f32x4;
typedef __attribute__((ext_vector_type(16))) float f32x16;
typedef __attribute__((ext_vector_type(8))) unsigned short ushort8;
typedef __attribute__((ext_vector_type(4))) unsigned short ushort4v;
typedef __attribute__((ext_vector_type(4))) unsigned uint4v;
typedef __attribute__((ext_vector_type(4))) float float4v;

#define MFMA16(a, b, c) __builtin_amdgcn_mfma_f32_16x16x32_bf16((a), (b), (c), 0, 0, 0)
#define MFMA32(a, b, c) __builtin_amdgcn_mfma_f32_32x32x16_bf16((a), (b), (c), 0, 0, 0)

__device__ __forceinline__ unsigned short f2bf(float f) {
  unsigned u = __builtin_bit_cast(unsigned, f);
  u += 0x7fffu + ((u >> 16) & 1u);           // RNE
  return (unsigned short)(u >> 16);
}

__device__ __forceinline__ unsigned pkbf(float lo, float hi) {  // bf16(lo)|bf16(hi)<<16
  unsigned d;
  asm("v_cvt_pk_bf16_f32 %0, %1, %2" : "=v"(d) : "v"(lo), "v"(hi));
  return d;
}

__device__ __forceinline__ float max3f(float a, float b, float c) {
  float d;
  asm("v_max3_f32 %0, %1, %2, %3" : "=v"(d) : "v"(a), "v"(b), "v"(c));
  return d;
}

__device__ __forceinline__ float exp2a(float x) {  // 2^x
  float d;
  asm("v_exp_f32 %0, %1" : "=v"(d) : "v"(x));
  return d;
}

__device__ __forceinline__ void gload_lds16(const void* g, void* l) {
  __builtin_amdgcn_global_load_lds(
      (const __attribute__((address_space(1))) void*)g,
      (__attribute__((address_space(3))) void*)l, 16, 0, 0);
}

// ---------------- prep: elementwise add + fp32->bf16 -----------------------
__global__ __launch_bounds__(256) void k_cvt(const float4v* __restrict__ x,
                                             const float4v* __restrict__ y,
                                             ushort4v* __restrict__ o, int n4) {
  int i = blockIdx.x * 256 + threadIdx.x;
  if (i >= n4) return;
  float4v a = x[i];
  if (y) { float4v b = y[i]; a = a + b; }
  ushort4v r;
  r[0] = f2bf(a[0]); r[1] = f2bf(a[1]); r[2] = f2bf(a[2]); r[3] = f2bf(a[3]);
  o[i] = r;
}

// ---------------- prep: kv -> a_k (kv+kv_pos) and a_v (kv) in one pass -----
__global__ __launch_bounds__(256) void k_cvt2(const float4v* __restrict__ x,
                                              const float4v* __restrict__ y,
                                              ushort4v* __restrict__ oa,
                                              ushort4v* __restrict__ ob, int n4) {
  int i = blockIdx.x * 256 + threadIdx.x;
  if (i >= n4) return;
  float4v a = x[i];
  float4v s = a + y[i];
  ushort4v ra, rb;
  ra[0] = f2bf(s[0]); ra[1] = f2bf(s[1]); ra[2] = f2bf(s[2]); ra[3] = f2bf(s[3]);
  rb[0] = f2bf(a[0]); rb[1] = f2bf(a[1]); rb[2] = f2bf(a[2]); rb[3] = f2bf(a[3]);
  oa[i] = ra; ob[i] = rb;
}

// ---------------- prep: weight transpose fp32[K][N] -> bf16[N][K] ----------
__global__ __launch_bounds__(256) void k_tr(const float* __restrict__ s0, const float* __restrict__ s1,
                                            const float* __restrict__ s2, const float* __restrict__ s3,
                                            unsigned short* __restrict__ d0, unsigned short* __restrict__ d1,
                                            unsigned short* __restrict__ d2, unsigned short* __restrict__ d3) {
  __shared__ float t[32][33];
  const float* S; unsigned short* D;
  switch (blockIdx.z) {
    case 0: S = s0; D = d0; break;
    case 1: S = s1; D = d1; break;
    case 2: S = s2; D = d2; break;
    default: S = s3; D = d3; break;
  }
  int x = threadIdx.x & 31, y = threadIdx.x >> 5;
  int r0 = blockIdx.y * 32, c0 = blockIdx.x * 32;
#pragma unroll
  for (int i = 0; i < 4; ++i) t[y + 8 * i][x] = S[(size_t)(r0 + y + 8 * i) * 2048 + c0 + x];
  __syncthreads();
#pragma unroll
  for (int i = 0; i < 4; ++i)
    D[(size_t)(c0 + y + 8 * i) * 2048 + r0 + x] = f2bf(t[x][y + 8 * i]);
}

// ---------------- prep: mask int32 -> bitmask (1 bit/key) ------------------
__global__ __launch_bounds__(256) void k_mask(const int* __restrict__ m,
                                              unsigned long long* __restrict__ out) {
  int i = blockIdx.x * 256 + threadIdx.x;
  unsigned long long b = __ballot(m[i] != 0);
  if ((threadIdx.x & 63) == 0) out[i >> 6] = b;
}

// ---------------- GEMM v2: 256x128 tile, BK=64, 8 waves, tri-buffer --------
// Counted-vmcnt pipeline: while computing tile t, tile t+1 is landed and
// tile t+2 is in flight (vmcnt(6) mid-loop, never 0 until the tail).
// Wave grid 2M x 4N; per-wave output 128x32 (8 i-frags x 2 j-frags).
// MODE 1: LN*scale*rsqrt(D)*log2e (Q) -> [B,H,S,D] bf16
// MODE 2: LN*scale (K)               -> [B,H,S,D] bf16
// MODE 3: fp32 direct to [M][2048] (final out-proj)
// MODE 4: V^T direct: A=wvt (M=2048=(h,d)), Bt=a_v (N=4096=(b,s));
//         store at Vtp[bh][d][(s&~15)|swap23(s&15)] bf16.
template <int MODE>
__global__ __launch_bounds__(512, 2) void k_gemm8(const unsigned short* __restrict__ A,
                                                  const unsigned short* __restrict__ Bt,
                                                  void* __restrict__ Cv,
                                                  const float* __restrict__ lnsc) {
  constexpr int K = 2048;
  constexpr int NT = 32;                 // K / 64
  constexpr int BUF = 49152;             // A 32KB + B 16KB per K-tile
  __shared__ __attribute__((aligned(16))) char smem[3 * BUF];  // 144 KB
  int tid = threadIdx.x;
  int lane = tid & 63, w = tid >> 6;
  int wr = w >> 2, wc = w & 3;           // 2 x 4 wave grid
  int r15 = lane & 15, blk = lane >> 4;
  int n0 = blockIdx.x * 128, m0 = blockIdx.y * 256;
  const unsigned short* Abase = A + (size_t)m0 * K;
  const unsigned short* Bbase = Bt + (size_t)n0 * K;
  f32x4 acc[8][2] = {};

  // per-thread staging descriptors (source XOR-pre-swizzled, dest linear)
  const unsigned short* ag[4]; int al[4];
  const unsigned short* bg[2]; int bl[2];
#pragma unroll
  for (int i = 0; i < 4; ++i) {
    int c = i * 512 + tid;               // 0..2047: A rows 0..255, 8 chunks/row
    int row = c >> 3, cc = c & 7;
    ag[i] = Abase + (size_t)row * K + ((cc ^ (row & 7)) * 8);
    al[i] = c * 16;
  }
#pragma unroll
  for (int i = 0; i < 2; ++i) {
    int c = i * 512 + tid;               // 0..1023: B rows 0..127
    int row = c >> 3, cc = c & 7;
    bg[i] = Bbase + (size_t)row * K + ((cc ^ (row & 7)) * 8);
    bl[i] = 32768 + c * 16;
  }

  auto stage = [&](int t) {
    char* buf = smem + (t % 3) * BUF;
    int kt = t * 64;
#pragma unroll
    for (int i = 0; i < 4; ++i) gload_lds16(ag[i] + kt, buf + al[i]);
#pragma unroll
    for (int i = 0; i < 2; ++i) gload_lds16(bg[i] + kt, buf + bl[i]);
  };

  stage(0);
  stage(1);

  for (int t = 0; t < NT; ++t) {
    if (t + 2 < NT) {
      stage(t + 2);                                     // 6 loads into buf[(t+2)%3]
      asm volatile("s_waitcnt vmcnt(6)" ::: "memory");  // tiles <= t+1 landed; t+2 in flight
    } else {
      asm volatile("s_waitcnt vmcnt(0)" ::: "memory");  // tail drain
    }
    __builtin_amdgcn_s_barrier();        // B1: all waves' tile-t loads drained
    __builtin_amdgcn_sched_barrier(0);
    const unsigned short* sA = (const unsigned short*)(smem + (t % 3) * BUF);
    const unsigned short* sB = (const unsigned short*)(smem + (t % 3) * BUF + 32768);
#pragma unroll
    for (int kk = 0; kk < 2; ++kk) {
      bf16x8 av[8], bv[2];
#pragma unroll
      for (int i = 0; i < 8; ++i) {
        int row = wr * 128 + i * 16 + r15;
        av[i] = *(const bf16x8*)&sA[row * 64 + (((kk * 4 + blk) ^ (row & 7)) * 8)];
      }
#pragma unroll
      for (int j = 0; j < 2; ++j) {
        int row = wc * 32 + j * 16 + r15;
        bv[j] = *(const bf16x8*)&sB[row * 64 + (((kk * 4 + blk) ^ (row & 7)) * 8)];
      }
#pragma unroll
      for (int i = 0; i < 8; ++i)
#pragma unroll
        for (int j = 0; j < 2; ++j) acc[i][j] = MFMA16(av[i], bv[j], acc[i][j]);
    }
    asm volatile("s_waitcnt lgkmcnt(0)" ::: "memory");  // my LDS reads done
    __builtin_amdgcn_s_barrier();        // B2: buf[t%3] safe to overwrite next iter
  }
  __syncthreads();                        // full fence before LDS reuse in epilogue

  if constexpr (MODE == 3) {
    float* C = (float*)Cv;
#pragma unroll
    for (int i = 0; i < 8; ++i)
#pragma unroll
      for (int r = 0; r < 4; ++r) {
        int rowl = wr * 128 + i * 16 + blk * 4 + r;   // C row=(lane>>4)*4+reg
#pragma unroll
        for (int j = 0; j < 2; ++j) {
          int coll = wc * 32 + j * 16 + r15;          // C col=lane&15
          C[(size_t)(m0 + rowl) * 2048 + n0 + coll] = acc[i][j][r];
        }
      }
  } else if constexpr (MODE == 4) {
    // V^T: rowg=(h,d), col=(b,s); key s stored at pos (s&~15)|swap23(r15)
    unsigned short* Vtp = (unsigned short*)Cv;
    int p15 = (r15 & 3) | ((r15 & 4) << 1) | ((r15 & 8) >> 1);
#pragma unroll
    for (int i = 0; i < 8; ++i)
#pragma unroll
      for (int r = 0; r < 4; ++r) {
        int rowg = m0 + wr * 128 + i * 16 + blk * 4 + r;  // (h,d)
        int h = rowg >> 7, d = rowg & 127;
#pragma unroll
        for (int j = 0; j < 2; ++j) {
          int col = n0 + wc * 32 + j * 16;                // (b, s&~15)
          int b = col >> 11, s16 = col & 2047;
          Vtp[(((size_t)(b * 16 + h) * 128 + d) * 2048) + s16 + p15] = f2bf(acc[i][j][r]);
        }
      }
  } else {
    // MODE 1/2: LayerNorm over the 128-col tile (= head_dim); head = blockIdx.x
    float* sSum = (float*)smem;            // [4][256]
    float* sSq  = (float*)smem + 1024;     // [4][256]
#pragma unroll
    for (int i = 0; i < 8; ++i)
#pragma unroll
      for (int r = 0; r < 4; ++r) {
        float v0 = acc[i][0][r], v1 = acc[i][1][r];
        float sm = v0 + v1, sq = v0 * v0 + v1 * v1;
        sm += __shfl_xor(sm, 1); sq += __shfl_xor(sq, 1);
        sm += __shfl_xor(sm, 2); sq += __shfl_xor(sq, 2);
        sm += __shfl_xor(sm, 4); sq += __shfl_xor(sq, 4);
        sm += __shfl_xor(sm, 8); sq += __shfl_xor(sq, 8);
        if (r15 == 0) {
          int rowl = wr * 128 + i * 16 + blk * 4 + r;
          sSum[wc * 256 + rowl] = sm;
          sSq[wc * 256 + rowl] = sq;
        }
      }
    __syncthreads();
    unsigned short* Hout = (unsigned short*)Cv;
    int h = blockIdx.x;
#pragma unroll
    for (int i = 0; i < 8; ++i)
#pragma unroll
      for (int r = 0; r < 4; ++r) {
        int rowl = wr * 128 + i * 16 + blk * 4 + r;
        float sm = (sSum[rowl] + sSum[256 + rowl]) + (sSum[512 + rowl] + sSum[768 + rowl]);
        float sq = (sSq[rowl] + sSq[256 + rowl]) + (sSq[512 + rowl] + sSq[768 + rowl]);
        float mean = sm * 0.0078125f;
        float var = sq * 0.0078125f - mean * mean;
        float rstd = rsqrtf(var + 1e-6f);
        int rowg = m0 + rowl;
        int b = rowg >> 11, s = rowg & 2047;
        unsigned short* orow = Hout + (((size_t)b * 16 + h) * 2048 + s) * 128;
#pragma unroll
        for (int j = 0; j < 2; ++j) {
          int d = wc * 32 + j * 16 + r15;
          float v = acc[i][j][r];
          // log2e folded in for Q: attention softmax runs in exp2 domain
          if constexpr (MODE == 1)
            v = (v - mean) * rstd * lnsc[d] * (0.08838834764831845f * 1.4426950408889634f);
          else
            v = (v - mean) * rstd * lnsc[d];
          orow[d] = f2bf(v);
        }
      }
  }
}

// ---------------- flash attention (r9-best): 32x32x16 MFMA + setprio -------
// 4 waves x 32 q = QBLK 128; KVBLK=64; dbuf 64 KB; grid 512 -> 2 blocks/CU.
// S^T = mfma32(K, Q): D col=lane&31=q, slot r -> key (r&3)+8*(r>>2)+4*hi.
// P packs feed PV A-frag in natural order because the global V^T carries the
// matching key-position permutation (MODE 4 store).
__global__ __launch_bounds__(256, 2) void k_attn(const unsigned short* __restrict__ Qh,
                                                 const unsigned short* __restrict__ Kh,
                                                 const unsigned short* __restrict__ Vtp,
                                                 const unsigned* __restrict__ maskb,
                                                 unsigned short* __restrict__ O) {
  __shared__ __attribute__((aligned(16))) char smem[65536];  // 2 x (sK 16K + sV 16K)
  int tid = threadIdx.x, w = tid >> 6;
  int lane = tid & 63;
  int q31 = lane & 31, hi = lane >> 5;
  int bh = blockIdx.y, b = bh >> 4, h = bh & 15;
  int qb = blockIdx.x * 128;
  size_t base = (size_t)bh * (2048 * 128);
  int qrow = qb + w * 32 + q31;

  bf16x8 qf[8];  // Q (B-operand): col=q31, k-window wd: d = wd*16 + hi*8 + j
  {
    const unsigned short* qp = Qh + base + (size_t)qrow * 128 + hi * 8;
#pragma unroll
    for (int wd = 0; wd < 8; ++wd) qf[wd] = *(const bf16x8*)(qp + wd * 16);
  }
  const unsigned* mrow = maskb + ((size_t)b * 2048 + qrow) * 64;

  // staging bases (kc=0): K [64 keys][128 d] linear rows, V^T [128 d][64 pos]
  const unsigned short* kgp[4];
  const unsigned short* vgp[4];
#pragma unroll
  for (int i = 0; i < 4; ++i) {
    int c = i * 256 + tid;              // 0..1023 chunk id
    int rr = c >> 4, cc = c & 15;       // K: row rr, 16B chunk cc
    kgp[i] = Kh + base + (size_t)rr * 128 + ((cc ^ (rr & 15)) * 8);
    int d = c >> 3, c8 = c & 7;         // V: row d, chunk c8
    vgp[i] = Vtp + base + (size_t)d * 2048 + ((c8 ^ (d & 7)) * 8);
  }

  f32x16 o[4] = {};                     // o[dt]: col d = dt*32+q31, rows=q slots
  float mv = -1e30f, ls = 0.f;

  // prologue: stage tile 0 into buf 0
#pragma unroll
  for (int i = 0; i < 4; ++i) {
    int c = i * 256 + tid;
    gload_lds16(kgp[i], smem + c * 16);
    gload_lds16(vgp[i], smem + 16384 + c * 16);
  }
  __syncthreads();

  int cur = 0;
  for (int kc = 0; kc < 2048; kc += 64) {
    if (kc + 64 < 2048) {  // stage next tile into the other buffer
      char* nb = smem + ((cur ^ 1) << 15);
#pragma unroll
      for (int i = 0; i < 4; ++i) {
        int c = i * 256 + tid;
        gload_lds16(kgp[i] + (size_t)(kc + 64) * 128, nb + c * 16);
        gload_lds16(vgp[i] + (kc + 64), nb + 16384 + c * 16);
      }
    }
    const unsigned short* sK = (const unsigned short*)(smem + (cur << 15));
    const unsigned short* sV = (const unsigned short*)(smem + (cur << 15) + 16384);

    unsigned mw0 = mrow[kc >> 5] >> (4 * hi);
    unsigned mw1 = mrow[(kc >> 5) + 1] >> (4 * hi);

    // S^T: 2 key-tiles x 8 d-windows. A=K frag: row=key=q31 (lane pos), k-window wd
    f32x16 st0 = {}, st1 = {};
    __builtin_amdgcn_s_setprio(1);
#pragma unroll
    for (int wd = 0; wd < 8; ++wd) {
      int ck = ((2 * wd + hi) ^ (q31 & 15)) * 8;
      bf16x8 k0 = *(const bf16x8*)&sK[q31 * 128 + ck];
      bf16x8 k1 = *(const bf16x8*)&sK[(32 + q31) * 128 + ck];
      st0 = MFMA32(k0, qf[wd], st0);
      st1 = MFMA32(k1, qf[wd], st1);
    }
    __builtin_amdgcn_s_setprio(0);

    // mask: slot r of tile kt = key kt*32 + (r&3)+8*(r>>2)+4*hi
    float pvv[32];
#pragma unroll
    for (int r = 0; r < 16; ++r) {
      int bit = (r & 3) + 8 * (r >> 2);  // compile-time
      pvv[r] = ((mw0 >> bit) & 1u) ? st0[r] : -1e30f;
      pvv[16 + r] = ((mw1 >> bit) & 1u) ? st1[r] : -1e30f;
    }
    // max over 32 slots (tree)
    float c0 = max3f(pvv[0], pvv[1], pvv[2]);
    float c1 = max3f(pvv[3], pvv[4], pvv[5]);
    float c2 = max3f(pvv[6], pvv[7], pvv[8]);
    float c3 = max3f(pvv[9], pvv[10], pvv[11]);
    float c4 = max3f(pvv[12], pvv[13], pvv[14]);
    float c5 = max3f(pvv[15], pvv[16], pvv[17]);
    float c6 = max3f(pvv[18], pvv[19], pvv[20]);
    float c7 = max3f(pvv[21], pvv[22], pvv[23]);
    float c8 = max3f(pvv[24], pvv[25], pvv[26]);
    float c9 = max3f(pvv[27], pvv[28], pvv[29]);
    float ca = fmaxf(pvv[30], pvv[31]);
    float t0 = max3f(c0, c1, c2);
    float t1 = max3f(c3, c4, c5);
    float t2 = max3f(c6, c7, c8);
    float t3 = max3f(c9, ca, t0);
    float cmax = max3f(t1, t2, t3);
    cmax = fmaxf(cmax, __shfl_xor(cmax, 32));

    if (!__all(cmax - mv <= 11.5f)) {  // defer-max: P bounded by 2^11.5
      float mnew = fmaxf(mv, cmax);
      float fac = exp2a(mv - mnew);
      ls *= fac;
      float fr[16];
#pragma unroll
      for (int r = 0; r < 16; ++r) fr[r] = __shfl(fac, (r & 3) + 8 * (r >> 2) + 4 * hi);
#pragma unroll
      for (int dt = 0; dt < 4; ++dt)
#pragma unroll
        for (int r = 0; r < 16; ++r) o[dt][r] *= fr[r];
      mv = mnew;
    }

#pragma unroll
    for (int t = 0; t < 32; ++t) pvv[t] = exp2a(pvv[t] - mv);
    {
      float s0 = 0.f, s1 = 0.f, s2 = 0.f, s3 = 0.f;
#pragma unroll
      for (int t = 0; t < 8; ++t) {
        s0 += pvv[t]; s1 += pvv[8 + t]; s2 += pvv[16 + t]; s3 += pvv[24 + t];
      }
      ls += (s0 + s1) + (s2 + s3);
    }

    // packs: window kw covers pvv[8*kw .. 8*kw+7] (= keys kw*16 + sigma(hi,j))
    bf16x8 pa[4];
#pragma unroll
    for (int kw = 0; kw < 4; ++kw) {
      uint4v pw;
#pragma unroll
      for (int m = 0; m < 4; ++m) pw[m] = pkbf(pvv[8 * kw + 2 * m], pvv[8 * kw + 2 * m + 1]);
      pa[kw] = __builtin_bit_cast(bf16x8, pw);
    }

    // PV: o[dt] += P(window kw) x V; B-frag = sV row dt*32+q31, chunk (2kw+hi)
    __builtin_amdgcn_s_setprio(1);
#pragma unroll
    for (int dt = 0; dt < 4; ++dt) {
      int vrow = dt * 32 + q31;
#pragma unroll
      for (int kw = 0; kw < 4; ++kw) {
        int cv = ((2 * kw + hi) ^ (q31 & 7)) * 8;
        bf16x8 vf = *(const bf16x8*)&sV[vrow * 64 + cv];
        o[dt] = MFMA32(pa[kw], vf, o[dt]);
      }
    }
    __builtin_amdgcn_s_setprio(0);
    __syncthreads();
    cur ^= 1;
  }

  // normalize factors: partner lane (l^32) holds the other half of the keys
  ls += __shfl_xor(ls, 32);
  float inv = 1.f / ls;
  float ir[16];
#pragma unroll
  for (int r = 0; r < 16; ++r) ir[r] = __shfl(inv, (r & 3) + 8 * (r >> 2) + 4 * hi);

  // epilogue: two 64-row passes through sO overlay (waves 0-1, then 2-3)
  float* sO = (float*)smem;
#pragma unroll
  for (int pass = 0; pass < 2; ++pass) {
    __syncthreads();
    if ((w >> 1) == pass) {
      int wl = w & 1;
#pragma unroll
      for (int dt = 0; dt < 4; ++dt)
#pragma unroll
        for (int r = 0; r < 16; ++r) {
          int qrl = wl * 32 + (r & 3) + 8 * (r >> 2) + 4 * hi;
          sO[qrl * 132 + dt * 32 + q31] = o[dt][r] * ir[r];
        }
    }
    __syncthreads();
    {
      int row = tid >> 2, d0 = (tid & 3) * 32;
      int grow = qb + pass * 64 + row;
      unsigned short* op = O + (size_t)(b * 2048 + grow) * 2048 + h * 128 + d0;
#pragma unroll
      for (int g = 0; g < 4; ++g) {
        ushort8 pk;
#pragma unroll
        for (int e = 0; e < 8; ++e) pk[e] = f2bf(sO[row * 132 + d0 + g * 8 + e]);
        *(ushort8*)(op + g * 8) = pk;
      }
    }
  }
}

// ---------------------------------------------------------------------------
extern "C" void kernel_launch(void* const* d_in, const int* in_sizes, int n_in,
                              void* d_out, int out_size, void* d_ws, size_t ws_size,
                              hipStream_t stream) {
  const float* q      = (const float*)d_in[0];
  const float* kv     = (const float*)d_in[1];
  const float* q_pos  = (const float*)d_in[2];
  const float* kv_pos = (const float*)d_in[3];
  const int*   mask   = (const int*)d_in[4];
  const float* wq     = (const float*)d_in[5];
  const float* wk     = (const float*)d_in[6];
  const float* wv     = (const float*)d_in[7];
  const float* qls    = (const float*)d_in[8];
  const float* kls    = (const float*)d_in[9];
  const float* wo     = (const float*)d_in[10];

  char* ws = (char*)d_ws;
  const size_t SZ_ACT = (size_t)4096 * 2048 * 2;  // 16 MiB
  const size_t SZ_W   = (size_t)2048 * 2048 * 2;  // 8 MiB
  unsigned short* a_q = (unsigned short*)(ws);
  unsigned short* a_k = (unsigned short*)(ws + SZ_ACT);
  unsigned short* a_v = (unsigned short*)(ws + 2 * SZ_ACT);
  unsigned short* Qh  = (unsigned short*)(ws + 3 * SZ_ACT);
  unsigned short* Kh  = (unsigned short*)(ws + 4 * SZ_ACT);
  unsigned short* wqt = (unsigned short*)(ws + 6 * SZ_ACT);
  unsigned short* wkt = (unsigned short*)(ws + 6 * SZ_ACT + SZ_W);
  unsigned short* wvt = (unsigned short*)(ws + 6 * SZ_ACT + 2 * SZ_W);
  unsigned short* wot = (unsigned short*)(ws + 6 * SZ_ACT + 3 * SZ_W);
  unsigned*       mkb = (unsigned*)(ws + 6 * SZ_ACT + 4 * SZ_W);
  unsigned short* Ob  = a_q;  // a_q dead after Q-projection; reuse for attn out
  unsigned short* Vtr = (unsigned short*)(ws + 5 * SZ_ACT);  // V^T (direct from MODE 4)

  const size_t NEED = 6 * SZ_ACT + 4 * SZ_W + (size_t)2 * 2048 * 64 * 4;
  if (ws_size < NEED) return;  // leave d_out poisoned -> visible failure

  k_cvt<<<8192, 256, 0, stream>>>((const float4v*)q, (const float4v*)q_pos, (ushort4v*)a_q, 2097152);
  k_cvt2<<<8192, 256, 0, stream>>>((const float4v*)kv, (const float4v*)kv_pos,
                                   (ushort4v*)a_k, (ushort4v*)a_v, 2097152);
  k_tr<<<dim3(64, 64, 4), 256, 0, stream>>>(wq, wk, wv, wo, wqt, wkt, wvt, wot);
  k_mask<<<32768, 256, 0, stream>>>(mask, (unsigned long long*)mkb);

  // Q/K projections: M=4096 (16 m-blocks), N=2048 (16 head-blocks) = 256 blocks
  k_gemm8<1><<<dim3(16, 16), 512, 0, stream>>>(a_q, wqt, Qh, qls);
  k_gemm8<2><<<dim3(16, 16), 512, 0, stream>>>(a_k, wkt, Kh, kls);
  // V^T directly: A=wvt (M=2048=(h,d), 8 m-blocks), Bt=a_v (N=4096=(b,s), 32)
  k_gemm8<4><<<dim3(32, 8), 512, 0, stream>>>(wvt, a_v, Vtr, nullptr);

  k_attn<<<dim3(16, 32), 256, 0, stream>>>(Qh, Kh, Vtr, mkb, Ob);

  // out-proj: M=4096, N=2048 -> fp32 d_out
  k_gemm8<3><<<dim3(16, 16), 512, 0, stream>>>(Ob, wot, d_out, nullptr);
}

// Round 13
// 316.174 us; speedup vs baseline: 1.0842x; 1.0315x over previous
//
#include <hip/hip_runtime.h>
#include <hip/hip_bf16.h>

// ---------------------------------------------------------------------------
// AttentionBlock: qkv-proj (+LN on q,k) -> masked flash attention -> out-proj
// B=2, S=2048, E=2048, H=16, D=128.
// GEMMs: tri-buffered counted-vmcnt pipeline (256x128 tile, BK=64, 8 waves,
// 3 LDS buffers, vmcnt(6) mid-loop) + XCD-clustered block remap (A-panel
// L2 residency: XCD k owns m-tiles {2k,2k+1}).
// Attention: bf16 MFMA 32x32x16, swapped QK^T, exp2-domain softmax, dbuf,
// XCD-clustered (XCD k owns bh {4k..4k+3}: K/V working set = 4MB = L2).
// V^T produced directly by swapped-operand GEMM (MODE 4, key-perm store).
// ---------------------------------------------------------------------------

typedef __attribute__((ext_vector_type(8))) __bf16 bf16x8;
typedef __attribute__((ext_vector_type(4))) float f32x4;
typedef __attribute__((ext_vector_type(16))) float f32x16;
typedef __attribute__((ext_vector_type(8))) unsigned short ushort8;
typedef __attribute__((ext_vector_type(4))) unsigned short ushort4v;
typedef __attribute__((ext_vector_type(4))) unsigned uint4v;
typedef __attribute__((ext_vector_type(4))) float float4v;

#define MFMA16(a, b, c) __builtin_amdgcn_mfma_f32_16x16x32_bf16((a), (b), (c), 0, 0, 0)
#define MFMA32(a, b, c) __builtin_amdgcn_mfma_f32_32x32x16_bf16((a), (b), (c), 0, 0, 0)

__device__ __forceinline__ unsigned short f2bf(float f) {
  unsigned u = __builtin_bit_cast(unsigned, f);
  u += 0x7fffu + ((u >> 16) & 1u);           // RNE
  return (unsigned short)(u >> 16);
}

__device__ __forceinline__ unsigned pkbf(float lo, float hi) {  // bf16(lo)|bf16(hi)<<16
  unsigned d;
  asm("v_cvt_pk_bf16_f32 %0, %1, %2" : "=v"(d) : "v"(lo), "v"(hi));
  return d;
}

__device__ __forceinline__ float max3f(float a, float b, float c) {
  float d;
  asm("v_max3_f32 %0, %1, %2, %3" : "=v"(d) : "v"(a), "v"(b), "v"(c));
  return d;
}

__device__ __forceinline__ float exp2a(float x) {  // 2^x
  float d;
  asm("v_exp_f32 %0, %1" : "=v"(d) : "v"(x));
  return d;
}

__device__ __forceinline__ void gload_lds16(const void* g, void* l) {
  __builtin_amdgcn_global_load_lds(
      (const __attribute__((address_space(1))) void*)g,
      (__attribute__((address_space(3))) void*)l, 16, 0, 0);
}

// ---------------- prep (fused): q+q_pos, kv+kv_pos & kv, mask bitmask ------
// blocks [0,8192): q-path; [8192,16384): kv-path; [16384,49152): mask.
__global__ __launch_bounds__(256) void k_prep(const float4v* __restrict__ q,
                                              const float4v* __restrict__ q_pos,
                                              const float4v* __restrict__ kv,
                                              const float4v* __restrict__ kv_pos,
                                              const int* __restrict__ mask,
                                              ushort4v* __restrict__ a_q,
                                              ushort4v* __restrict__ a_k,
                                              ushort4v* __restrict__ a_v,
                                              unsigned long long* __restrict__ mkb) {
  int bx = blockIdx.x, tid = threadIdx.x;
  if (bx < 8192) {
    int i = bx * 256 + tid;
    float4v a = q[i] + q_pos[i];
    ushort4v r;
    r[0] = f2bf(a[0]); r[1] = f2bf(a[1]); r[2] = f2bf(a[2]); r[3] = f2bf(a[3]);
    a_q[i] = r;
  } else if (bx < 16384) {
    int i = (bx - 8192) * 256 + tid;
    float4v a = kv[i];
    float4v s = a + kv_pos[i];
    ushort4v ra, rb;
    ra[0] = f2bf(s[0]); ra[1] = f2bf(s[1]); ra[2] = f2bf(s[2]); ra[3] = f2bf(s[3]);
    rb[0] = f2bf(a[0]); rb[1] = f2bf(a[1]); rb[2] = f2bf(a[2]); rb[3] = f2bf(a[3]);
    a_k[i] = ra; a_v[i] = rb;
  } else {
    int i = (bx - 16384) * 256 + tid;
    unsigned long long b = __ballot(mask[i] != 0);
    if ((tid & 63) == 0) mkb[i >> 6] = b;
  }
}

// ---------------- prep: weight transpose fp32[K][N] -> bf16[N][K] ----------
__global__ __launch_bounds__(256) void k_tr(const float* __restrict__ s0, const float* __restrict__ s1,
                                            const float* __restrict__ s2, const float* __restrict__ s3,
                                            unsigned short* __restrict__ d0, unsigned short* __restrict__ d1,
                                            unsigned short* __restrict__ d2, unsigned short* __restrict__ d3) {
  __shared__ float t[32][33];
  const float* S; unsigned short* D;
  switch (blockIdx.z) {
    case 0: S = s0; D = d0; break;
    case 1: S = s1; D = d1; break;
    case 2: S = s2; D = d2; break;
    default: S = s3; D = d3; break;
  }
  int x = threadIdx.x & 31, y = threadIdx.x >> 5;
  int r0 = blockIdx.y * 32, c0 = blockIdx.x * 32;
#pragma unroll
  for (int i = 0; i < 4; ++i) t[y + 8 * i][x] = S[(size_t)(r0 + y + 8 * i) * 2048 + c0 + x];
  __syncthreads();
#pragma unroll
  for (int i = 0; i < 4; ++i)
    D[(size_t)(c0 + y + 8 * i) * 2048 + r0 + x] = f2bf(t[x][y + 8 * i]);
}

// ---------------- GEMM v2: 256x128 tile, BK=64, 8 waves, tri-buffer --------
// Counted-vmcnt pipeline + XCD-clustered block remap (grid must be 256).
// MODE 1: LN*scale*rsqrt(D)*log2e (Q) -> [B,H,S,D] bf16
// MODE 2: LN*scale (K)               -> [B,H,S,D] bf16
// MODE 3: fp32 direct to [M][2048] (final out-proj)
// MODE 4: V^T direct: A=wvt (M=2048=(h,d)), Bt=a_v (N=4096=(b,s));
//         store at Vtp[bh][d][(s&~15)|swap23(s&15)] bf16.
template <int MODE>
__global__ __launch_bounds__(512, 2) void k_gemm8(const unsigned short* __restrict__ A,
                                                  const unsigned short* __restrict__ Bt,
                                                  void* __restrict__ Cv,
                                                  const float* __restrict__ lnsc) {
  constexpr int K = 2048;
  constexpr int NT = 32;                 // K / 64
  constexpr int BUF = 49152;             // A 32KB + B 16KB per K-tile
  __shared__ __attribute__((aligned(16))) char smem[3 * BUF];  // 144 KB
  int tid = threadIdx.x;
  int lane = tid & 63, w = tid >> 6;
  int wr = w >> 2, wc = w & 3;           // 2 x 4 wave grid
  int r15 = lane & 15, blk = lane >> 4;
  // XCD-clustered remap (bijective for grid==256): same-A blocks share an XCD
  int L = blockIdx.y * gridDim.x + blockIdx.x;
  int xcd = L & 7, slot = L >> 3;        // slot 0..31
  int mt, nt;
  if constexpr (MODE == 4) { mt = xcd; nt = slot; }          // M=2048: 8 m-tiles
  else { mt = xcd * 2 + (slot >> 4); nt = slot & 15; }       // M=4096: 16 m-tiles
  int n0 = nt * 128, m0 = mt * 256;
  const unsigned short* Abase = A + (size_t)m0 * K;
  const unsigned short* Bbase = Bt + (size_t)n0 * K;
  f32x4 acc[8][2] = {};

  // per-thread staging descriptors (source XOR-pre-swizzled, dest linear)
  const unsigned short* ag[4]; int al[4];
  const unsigned short* bg[2]; int bl[2];
#pragma unroll
  for (int i = 0; i < 4; ++i) {
    int c = i * 512 + tid;               // 0..2047: A rows 0..255, 8 chunks/row
    int row = c >> 3, cc = c & 7;
    ag[i] = Abase + (size_t)row * K + ((cc ^ (row & 7)) * 8);
    al[i] = c * 16;
  }
#pragma unroll
  for (int i = 0; i < 2; ++i) {
    int c = i * 512 + tid;               // 0..1023: B rows 0..127
    int row = c >> 3, cc = c & 7;
    bg[i] = Bbase + (size_t)row * K + ((cc ^ (row & 7)) * 8);
    bl[i] = 32768 + c * 16;
  }

  auto stage = [&](int t) {
    char* buf = smem + (t % 3) * BUF;
    int kt = t * 64;
#pragma unroll
    for (int i = 0; i < 4; ++i) gload_lds16(ag[i] + kt, buf + al[i]);
#pragma unroll
    for (int i = 0; i < 2; ++i) gload_lds16(bg[i] + kt, buf + bl[i]);
  };

  stage(0);
  stage(1);

  for (int t = 0; t < NT; ++t) {
    if (t + 2 < NT) {
      stage(t + 2);                                     // 6 loads into buf[(t+2)%3]
      asm volatile("s_waitcnt vmcnt(6)" ::: "memory");  // tiles <= t+1 landed; t+2 in flight
    } else {
      asm volatile("s_waitcnt vmcnt(0)" ::: "memory");  // tail drain
    }
    __builtin_amdgcn_s_barrier();        // B1: all waves' tile-t loads drained
    __builtin_amdgcn_sched_barrier(0);
    const unsigned short* sA = (const unsigned short*)(smem + (t % 3) * BUF);
    const unsigned short* sB = (const unsigned short*)(smem + (t % 3) * BUF + 32768);
#pragma unroll
    for (int kk = 0; kk < 2; ++kk) {
      bf16x8 av[8], bv[2];
#pragma unroll
      for (int i = 0; i < 8; ++i) {
        int row = wr * 128 + i * 16 + r15;
        av[i] = *(const bf16x8*)&sA[row * 64 + (((kk * 4 + blk) ^ (row & 7)) * 8)];
      }
#pragma unroll
      for (int j = 0; j < 2; ++j) {
        int row = wc * 32 + j * 16 + r15;
        bv[j] = *(const bf16x8*)&sB[row * 64 + (((kk * 4 + blk) ^ (row & 7)) * 8)];
      }
#pragma unroll
      for (int i = 0; i < 8; ++i)
#pragma unroll
        for (int j = 0; j < 2; ++j) acc[i][j] = MFMA16(av[i], bv[j], acc[i][j]);
    }
    asm volatile("s_waitcnt lgkmcnt(0)" ::: "memory");  // my LDS reads done
    __builtin_amdgcn_s_barrier();        // B2: buf[t%3] safe to overwrite next iter
  }
  __syncthreads();                        // full fence before LDS reuse in epilogue

  if constexpr (MODE == 3) {
    float* C = (float*)Cv;
#pragma unroll
    for (int i = 0; i < 8; ++i)
#pragma unroll
      for (int r = 0; r < 4; ++r) {
        int rowl = wr * 128 + i * 16 + blk * 4 + r;   // C row=(lane>>4)*4+reg
#pragma unroll
        for (int j = 0; j < 2; ++j) {
          int coll = wc * 32 + j * 16 + r15;          // C col=lane&15
          C[(size_t)(m0 + rowl) * 2048 + n0 + coll] = acc[i][j][r];
        }
      }
  } else if constexpr (MODE == 4) {
    // V^T: rowg=(h,d), col=(b,s); key s stored at pos (s&~15)|swap23(r15)
    unsigned short* Vtp = (unsigned short*)Cv;
    int p15 = (r15 & 3) | ((r15 & 4) << 1) | ((r15 & 8) >> 1);
#pragma unroll
    for (int i = 0; i < 8; ++i)
#pragma unroll
      for (int r = 0; r < 4; ++r) {
        int rowg = m0 + wr * 128 + i * 16 + blk * 4 + r;  // (h,d)
        int h = rowg >> 7, d = rowg & 127;
#pragma unroll
        for (int j = 0; j < 2; ++j) {
          int col = n0 + wc * 32 + j * 16;                // (b, s&~15)
          int b = col >> 11, s16 = col & 2047;
          Vtp[(((size_t)(b * 16 + h) * 128 + d) * 2048) + s16 + p15] = f2bf(acc[i][j][r]);
        }
      }
  } else {
    // MODE 1/2: LayerNorm over the 128-col tile (= head_dim); head = nt
    float* sSum = (float*)smem;            // [4][256]
    float* sSq  = (float*)smem + 1024;     // [4][256]
#pragma unroll
    for (int i = 0; i < 8; ++i)
#pragma unroll
      for (int r = 0; r < 4; ++r) {
        float v0 = acc[i][0][r], v1 = acc[i][1][r];
        float sm = v0 + v1, sq = v0 * v0 + v1 * v1;
        sm += __shfl_xor(sm, 1); sq += __shfl_xor(sq, 1);
        sm += __shfl_xor(sm, 2); sq += __shfl_xor(sq, 2);
        sm += __shfl_xor(sm, 4); sq += __shfl_xor(sq, 4);
        sm += __shfl_xor(sm, 8); sq += __shfl_xor(sq, 8);
        if (r15 == 0) {
          int rowl = wr * 128 + i * 16 + blk * 4 + r;
          sSum[wc * 256 + rowl] = sm;
          sSq[wc * 256 + rowl] = sq;
        }
      }
    __syncthreads();
    unsigned short* Hout = (unsigned short*)Cv;
    int h = nt;
#pragma unroll
    for (int i = 0; i < 8; ++i)
#pragma unroll
      for (int r = 0; r < 4; ++r) {
        int rowl = wr * 128 + i * 16 + blk * 4 + r;
        float sm = (sSum[rowl] + sSum[256 + rowl]) + (sSum[512 + rowl] + sSum[768 + rowl]);
        float sq = (sSq[rowl] + sSq[256 + rowl]) + (sSq[512 + rowl] + sSq[768 + rowl]);
        float mean = sm * 0.0078125f;
        float var = sq * 0.0078125f - mean * mean;
        float rstd = rsqrtf(var + 1e-6f);
        int rowg = m0 + rowl;
        int b = rowg >> 11, s = rowg & 2047;
        unsigned short* orow = Hout + (((size_t)b * 16 + h) * 2048 + s) * 128;
#pragma unroll
        for (int j = 0; j < 2; ++j) {
          int d = wc * 32 + j * 16 + r15;
          float v = acc[i][j][r];
          // log2e folded in for Q: attention softmax runs in exp2 domain
          if constexpr (MODE == 1)
            v = (v - mean) * rstd * lnsc[d] * (0.08838834764831845f * 1.4426950408889634f);
          else
            v = (v - mean) * rstd * lnsc[d];
          orow[d] = f2bf(v);
        }
      }
  }
}

// ---------------- flash attention: 32x32x16 MFMA, XCD-clustered ------------
// 4 waves x 32 q = QBLK 128; KVBLK=64; dbuf 64 KB; grid 512 -> 2 blocks/CU.
// XCD k owns bh {4k..4k+3} (K/V working set 4MB = L2 per XCD).
// S^T = mfma32(K, Q): D col=lane&31=q, slot r -> key (r&3)+8*(r>>2)+4*hi.
// P packs feed PV A-frag in natural order (V^T carries the key-perm, MODE 4).
__global__ __launch_bounds__(256, 2) void k_attn(const unsigned short* __restrict__ Qh,
                                                 const unsigned short* __restrict__ Kh,
                                                 const unsigned short* __restrict__ Vtp,
                                                 const unsigned* __restrict__ maskb,
                                                 unsigned short* __restrict__ O) {
  __shared__ __attribute__((aligned(16))) char smem[65536];  // 2 x (sK 16K + sV 16K)
  int tid = threadIdx.x, w = tid >> 6;
  int lane = tid & 63;
  int q31 = lane & 31, hi = lane >> 5;
  // XCD-clustered remap (bijective: grid = 16 x 32 = 512)
  int L = blockIdx.y * 16 + blockIdx.x;
  int xcd = L & 7, slot = L >> 3;        // slot 0..63
  int bh = xcd * 4 + (slot >> 4);
  int qb = (slot & 15) * 128;
  int b = bh >> 4, h = bh & 15;
  size_t base = (size_t)bh * (2048 * 128);
  int qrow = qb + w * 32 + q31;

  bf16x8 qf[8];  // Q (B-operand): col=q31, k-window wd: d = wd*16 + hi*8 + j
  {
    const unsigned short* qp = Qh + base + (size_t)qrow * 128 + hi * 8;
#pragma unroll
    for (int wd = 0; wd < 8; ++wd) qf[wd] = *(const bf16x8*)(qp + wd * 16);
  }
  const unsigned* mrow = maskb + ((size_t)b * 2048 + qrow) * 64;

  // staging bases (kc=0): K [64 keys][128 d] linear rows, V^T [128 d][64 pos]
  const unsigned short* kgp[4];
  const unsigned short* vgp[4];
#pragma unroll
  for (int i = 0; i < 4; ++i) {
    int c = i * 256 + tid;              // 0..1023 chunk id
    int rr = c >> 4, cc = c & 15;       // K: row rr, 16B chunk cc
    kgp[i] = Kh + base + (size_t)rr * 128 + ((cc ^ (rr & 15)) * 8);
    int d = c >> 3, c8 = c & 7;         // V: row d, chunk c8
    vgp[i] = Vtp + base + (size_t)d * 2048 + ((c8 ^ (d & 7)) * 8);
  }

  f32x16 o[4] = {};                     // o[dt]: col d = dt*32+q31, rows=q slots
  float mv = -1e30f, ls = 0.f;

  // prologue: stage tile 0 into buf 0
#pragma unroll
  for (int i = 0; i < 4; ++i) {
    int c = i * 256 + tid;
    gload_lds16(kgp[i], smem + c * 16);
    gload_lds16(vgp[i], smem + 16384 + c * 16);
  }
  __syncthreads();

  int cur = 0;
  for (int kc = 0; kc < 2048; kc += 64) {
    if (kc + 64 < 2048) {  // stage next tile into the other buffer
      char* nb = smem + ((cur ^ 1) << 15);
#pragma unroll
      for (int i = 0; i < 4; ++i) {
        int c = i * 256 + tid;
        gload_lds16(kgp[i] + (size_t)(kc + 64) * 128, nb + c * 16);
        gload_lds16(vgp[i] + (kc + 64), nb + 16384 + c * 16);
      }
    }
    const unsigned short* sK = (const unsigned short*)(smem + (cur << 15));
    const unsigned short* sV = (const unsigned short*)(smem + (cur << 15) + 16384);

    unsigned mw0 = mrow[kc >> 5] >> (4 * hi);
    unsigned mw1 = mrow[(kc >> 5) + 1] >> (4 * hi);

    // S^T: 2 key-tiles x 8 d-windows. A=K frag: row=key=q31 (lane pos), k-window wd
    f32x16 st0 = {}, st1 = {};
    __builtin_amdgcn_s_setprio(1);
#pragma unroll
    for (int wd = 0; wd < 8; ++wd) {
      int ck = ((2 * wd + hi) ^ (q31 & 15)) * 8;
      bf16x8 k0 = *(const bf16x8*)&sK[q31 * 128 + ck];
      bf16x8 k1 = *(const bf16x8*)&sK[(32 + q31) * 128 + ck];
      st0 = MFMA32(k0, qf[wd], st0);
      st1 = MFMA32(k1, qf[wd], st1);
    }
    __builtin_amdgcn_s_setprio(0);

    // mask: slot r of tile kt = key kt*32 + (r&3)+8*(r>>2)+4*hi
    float pvv[32];
#pragma unroll
    for (int r = 0; r < 16; ++r) {
      int bit = (r & 3) + 8 * (r >> 2);  // compile-time
      pvv[r] = ((mw0 >> bit) & 1u) ? st0[r] : -1e30f;
      pvv[16 + r] = ((mw1 >> bit) & 1u) ? st1[r] : -1e30f;
    }
    // max over 32 slots (tree)
    float c0 = max3f(pvv[0], pvv[1], pvv[2]);
    float c1 = max3f(pvv[3], pvv[4], pvv[5]);
    float c2 = max3f(pvv[6], pvv[7], pvv[8]);
    float c3 = max3f(pvv[9], pvv[10], pvv[11]);
    float c4 = max3f(pvv[12], pvv[13], pvv[14]);
    float c5 = max3f(pvv[15], pvv[16], pvv[17]);
    float c6 = max3f(pvv[18], pvv[19], pvv[20]);
    float c7 = max3f(pvv[21], pvv[22], pvv[23]);
    float c8 = max3f(pvv[24], pvv[25], pvv[26]);
    float c9 = max3f(pvv[27], pvv[28], pvv[29]);
    float ca = fmaxf(pvv[30], pvv[31]);
    float t0 = max3f(c0, c1, c2);
    float t1 = max3f(c3, c4, c5);
    float t2 = max3f(c6, c7, c8);
    float t3 = max3f(c9, ca, t0);
    float cmax = max3f(t1, t2, t3);
    cmax = fmaxf(cmax, __shfl_xor(cmax, 32));

    if (!__all(cmax - mv <= 11.5f)) {  // defer-max: P bounded by 2^11.5
      float mnew = fmaxf(mv, cmax);
      float fac = exp2a(mv - mnew);
      ls *= fac;
      float fr[16];
#pragma unroll
      for (int r = 0; r < 16; ++r) fr[r] = __shfl(fac, (r & 3) + 8 * (r >> 2) + 4 * hi);
#pragma unroll
      for (int dt = 0; dt < 4; ++dt)
#pragma unroll
        for (int r = 0; r < 16; ++r) o[dt][r] *= fr[r];
      mv = mnew;
    }

#pragma unroll
    for (int t = 0; t < 32; ++t) pvv[t] = exp2a(pvv[t] - mv);
    {
      float s0 = 0.f, s1 = 0.f, s2 = 0.f, s3 = 0.f;
#pragma unroll
      for (int t = 0; t < 8; ++t) {
        s0 += pvv[t]; s1 += pvv[8 + t]; s2 += pvv[16 + t]; s3 += pvv[24 + t];
      }
      ls += (s0 + s1) + (s2 + s3);
    }

    // packs: window kw covers pvv[8*kw .. 8*kw+7] (= keys kw*16 + sigma(hi,j))
    bf16x8 pa[4];
#pragma unroll
    for (int kw = 0; kw < 4; ++kw) {
      uint4v pw;
#pragma unroll
      for (int m = 0; m < 4; ++m) pw[m] = pkbf(pvv[8 * kw + 2 * m], pvv[8 * kw + 2 * m + 1]);
      pa[kw] = __builtin_bit_cast(bf16x8, pw);
    }

    // PV: o[dt] += P(window kw) x V; B-frag = sV row dt*32+q31, chunk (2kw+hi)
    __builtin_amdgcn_s_setprio(1);
#pragma unroll
    for (int dt = 0; dt < 4; ++dt) {
      int vrow = dt * 32 + q31;
#pragma unroll
      for (int kw = 0; kw < 4; ++kw) {
        int cv = ((2 * kw + hi) ^ (q31 & 7)) * 8;
        bf16x8 vf = *(const bf16x8*)&sV[vrow * 64 + cv];
        o[dt] = MFMA32(pa[kw], vf, o[dt]);
      }
    }
    __builtin_amdgcn_s_setprio(0);
    __syncthreads();
    cur ^= 1;
  }

  // normalize factors: partner lane (l^32) holds the other half of the keys
  ls += __shfl_xor(ls, 32);
  float inv = 1.f / ls;
  float ir[16];
#pragma unroll
  for (int r = 0; r < 16; ++r) ir[r] = __shfl(inv, (r & 3) + 8 * (r >> 2) + 4 * hi);

  // epilogue: two 64-row passes through sO overlay (waves 0-1, then 2-3)
  float* sO = (float*)smem;
#pragma unroll
  for (int pass = 0; pass < 2; ++pass) {
    __syncthreads();
    if ((w >> 1) == pass) {
      int wl = w & 1;
#pragma unroll
      for (int dt = 0; dt < 4; ++dt)
#pragma unroll
        for (int r = 0; r < 16; ++r) {
          int qrl = wl * 32 + (r & 3) + 8 * (r >> 2) + 4 * hi;
          sO[qrl * 132 + dt * 32 + q31] = o[dt][r] * ir[r];
        }
    }
    __syncthreads();
    {
      int row = tid >> 2, d0 = (tid & 3) * 32;
      int grow = qb + pass * 64 + row;
      unsigned short* op = O + (size_t)(b * 2048 + grow) * 2048 + h * 128 + d0;
#pragma unroll
      for (int g = 0; g < 4; ++g) {
        ushort8 pk;
#pragma unroll
        for (int e = 0; e < 8; ++e) pk[e] = f2bf(sO[row * 132 + d0 + g * 8 + e]);
        *(ushort8*)(op + g * 8) = pk;
      }
    }
  }
}

// ---------------------------------------------------------------------------
extern "C" void kernel_launch(void* const* d_in, const int* in_sizes, int n_in,
                              void* d_out, int out_size, void* d_ws, size_t ws_size,
                              hipStream_t stream) {
  const float* q      = (const float*)d_in[0];
  const float* kv     = (const float*)d_in[1];
  const float* q_pos  = (const float*)d_in[2];
  const float* kv_pos = (const float*)d_in[3];
  const int*   mask   = (const int*)d_in[4];
  const float* wq     = (const float*)d_in[5];
  const float* wk     = (const float*)d_in[6];
  const float* wv     = (const float*)d_in[7];
  const float* qls    = (const float*)d_in[8];
  const float* kls    = (const float*)d_in[9];
  const float* wo     = (const float*)d_in[10];

  char* ws = (char*)d_ws;
  const size_t SZ_ACT = (size_t)4096 * 2048 * 2;  // 16 MiB
  const size_t SZ_W   = (size_t)2048 * 2048 * 2;  // 8 MiB
  unsigned short* a_q = (unsigned short*)(ws);
  unsigned short* a_k = (unsigned short*)(ws + SZ_ACT);
  unsigned short* a_v = (unsigned short*)(ws + 2 * SZ_ACT);
  unsigned short* Qh  = (unsigned short*)(ws + 3 * SZ_ACT);
  unsigned short* Kh  = (unsigned short*)(ws + 4 * SZ_ACT);
  unsigned short* wqt = (unsigned short*)(ws + 6 * SZ_ACT);
  unsigned short* wkt = (unsigned short*)(ws + 6 * SZ_ACT + SZ_W);
  unsigned short* wvt = (unsigned short*)(ws + 6 * SZ_ACT + 2 * SZ_W);
  unsigned short* wot = (unsigned short*)(ws + 6 * SZ_ACT + 3 * SZ_W);
  unsigned*       mkb = (unsigned*)(ws + 6 * SZ_ACT + 4 * SZ_W);
  unsigned short* Ob  = a_q;  // a_q dead after Q-projection; reuse for attn out
  unsigned short* Vtr = (unsigned short*)(ws + 5 * SZ_ACT);  // V^T (direct from MODE 4)

  const size_t NEED = 6 * SZ_ACT + 4 * SZ_W + (size_t)2 * 2048 * 64 * 4;
  if (ws_size < NEED) return;  // leave d_out poisoned -> visible failure

  k_prep<<<49152, 256, 0, stream>>>((const float4v*)q, (const float4v*)q_pos,
                                    (const float4v*)kv, (const float4v*)kv_pos, mask,
                                    (ushort4v*)a_q, (ushort4v*)a_k, (ushort4v*)a_v,
                                    (unsigned long long*)mkb);
  k_tr<<<dim3(64, 64, 4), 256, 0, stream>>>(wq, wk, wv, wo, wqt, wkt, wvt, wot);

  // Q/K projections: M=4096 (16 m-blocks), N=2048 (16 head-blocks) = 256 blocks
  k_gemm8<1><<<dim3(16, 16), 512, 0, stream>>>(a_q, wqt, Qh, qls);
  k_gemm8<2><<<dim3(16, 16), 512, 0, stream>>>(a_k, wkt, Kh, kls);
  // V^T directly: A=wvt (M=2048=(h,d), 8 m-blocks), Bt=a_v (N=4096=(b,s), 32)
  k_gemm8<4><<<dim3(32, 8), 512, 0, stream>>>(wvt, a_v, Vtr, nullptr);

  k_attn<<<dim3(16, 32), 256, 0, stream>>>(Qh, Kh, Vtr, mkb, Ob);

  // out-proj: M=4096, N=2048 -> fp32 d_out
  k_gemm8<3><<<dim3(16, 16), 512, 0, stream>>>(Ob, wot, d_out, nullptr);
}